// Round 5
// baseline (1320.881 us; speedup 1.0000x reference)
//
#include <hip/hip_runtime.h>

#define HID 128
#define NLAYER 4

typedef unsigned short u16;
typedef __attribute__((ext_vector_type(8))) unsigned short u16x8;
typedef __attribute__((ext_vector_type(8))) short short8;
typedef __attribute__((ext_vector_type(4))) float floatx4;

__device__ __forceinline__ float bf2f(u16 u) {
    union { unsigned int i; float f; } v; v.i = ((unsigned int)u) << 16; return v.f;
}
__device__ __forceinline__ u16 f2bf(float f) {
    union { float f; unsigned int i; } v; v.f = f;
    unsigned int r = v.i + 0x7FFFu + ((v.i >> 16) & 1u);
    return (u16)(r >> 16);
}

// ---------------------------------------------------------------------------
__device__ __forceinline__ int lowbound(const int* __restrict__ a, int n, int v) {
    int lo = 0, hi = n;
    while (lo < hi) {
        int mid = (lo + hi) >> 1;
        if (a[mid] < v) lo = mid + 1; else hi = mid;
    }
    return lo;
}

// ---------------------------------------------------------------------------
// Weight prep: fp32 -> bf16, transposed to [enc][l][n][k].
// ---------------------------------------------------------------------------
__global__ void prep_weights(const float* __restrict__ W1, const float* __restrict__ W2,
                             u16* __restrict__ W1t, u16* __restrict__ W2t) {
    const int T = 3 * NLAYER * 128 * 256;  // 393216
    int o = blockIdx.x * blockDim.x + threadIdx.x;
    if (o < T) {
        int k = o & 127, n = (o >> 7) & 255, el = o >> 15;
        W1t[o] = f2bf(W1[((size_t)el * 128 + k) * 256 + n]);
    } else if (o < 2 * T) {
        int o2 = o - T;
        int k = o2 & 255, n = (o2 >> 8) & 127, el = o2 >> 15;
        W2t[o2] = f2bf(W2[((size_t)el * 256 + k) * 128 + n]);
    }
}

// ---------------------------------------------------------------------------
// CSR build v2: bucket by dst>>6 so the final srcidx/rowptr writes are done by
// a SINGLE block per bucket (single-owner, full-line writes, no cross-XCD
// partial-line flush).  grid.y selects graph (0=drug, 1=solvent).
// ---------------------------------------------------------------------------
__global__ void countA(const int* __restrict__ de, const int* __restrict__ se,
                       int* __restrict__ bcnt, int Ed, int Es, int NBU) {
    const int g = blockIdx.y;
    const int* ei = g ? se : de;
    const int E = g ? Es : Ed;
    int e = blockIdx.x * 256 + threadIdx.x;
    if (e < E) atomicAdd(&bcnt[g * NBU + (ei[E + e] >> 6)], 1);
}

// one block per graph; NBU <= 1024
__global__ __launch_bounds__(1024) void scanB(const int* __restrict__ bcnt,
                                              int* __restrict__ bbase, int NBU) {
    const int g = blockIdx.x;
    __shared__ int s[1024];
    const int tid = threadIdx.x;
    int v = (tid < NBU) ? bcnt[g * NBU + tid] : 0;
    s[tid] = v;
    __syncthreads();
    for (int o = 1; o < 1024; o <<= 1) {
        int tv = (tid >= o) ? s[tid - o] : 0;
        __syncthreads();
        s[tid] += tv;
        __syncthreads();
    }
    if (tid < NBU) bbase[g * (NBU + 1) + tid] = s[tid] - v;  // exclusive
    if (tid == 1023) bbase[g * (NBU + 1) + NBU] = s[1023];
}

__global__ void scatterA(const int* __restrict__ de, const int* __restrict__ se,
                         const int* __restrict__ bbase, int* __restrict__ bpos,
                         int2* __restrict__ ebufd, int2* __restrict__ ebufs,
                         int Ed, int Es, int NBU) {
    const int g = blockIdx.y;
    const int* ei = g ? se : de;
    int2* ebuf = g ? ebufs : ebufd;
    const int E = g ? Es : Ed;
    int e = blockIdx.x * 256 + threadIdx.x;
    if (e < E) {
        const int src = ei[e], dst = ei[E + e];
        const int b = dst >> 6;
        const int pos = bbase[g * (NBU + 1) + b] + atomicAdd(&bpos[g * NBU + b], 1);
        ebuf[pos] = make_int2(src, dst);
    }
}

// one block per bucket: builds rowptr + grouped srcidx for 64 nodes
__global__ __launch_bounds__(256) void passB(const int2* __restrict__ ebufd,
                                             const int2* __restrict__ ebufs,
                                             const int* __restrict__ bbase,
                                             int* __restrict__ rpd, int* __restrict__ rps,
                                             int* __restrict__ sid, int* __restrict__ sis,
                                             int N, int NBU) {
    const int g = blockIdx.y;
    const int b = blockIdx.x;
    const int2* ebuf = g ? ebufs : ebufd;
    int* rowptr = g ? rps : rpd;
    int* srcidx = g ? sis : sid;
    const int lo = bbase[g * (NBU + 1) + b];
    const int hi = bbase[g * (NBU + 1) + b + 1];
    const int base_node = b << 6;
    const int tid = threadIdx.x;

    __shared__ int hist[64], pref[64];
    if (tid < 64) hist[tid] = 0;
    __syncthreads();
    for (int e = lo + tid; e < hi; e += 256)
        atomicAdd(&hist[ebuf[e].y - base_node], 1);
    __syncthreads();
    if (tid == 0) {
        int acc = 0;
        for (int j = 0; j < 64; j++) { pref[j] = acc; acc += hist[j]; }
    }
    __syncthreads();
    if (tid < 64) {
        const int node = base_node + tid;
        if (node < N) rowptr[node] = lo + pref[tid];
        hist[tid] = 0;
    }
    if (b == NBU - 1 && tid == 0) rowptr[N] = hi;
    __syncthreads();
    for (int e = lo + tid; e < hi; e += 256) {
        const int2 ed = ebuf[e];
        const int d = ed.y - base_node;
        const int r = atomicAdd(&hist[d], 1);
        srcidx[lo + pref[d] + r] = ed.x;
    }
}

// ---------------------------------------------------------------------------
// Atom encoder: h = x @ aW + ab  (fp32 compute, bf16 store). grid.z = slot.
// ---------------------------------------------------------------------------
__global__ void atom_kernel(const float* __restrict__ dx, const float* __restrict__ sx,
                            const float* __restrict__ aW, const float* __restrict__ ab,
                            u16* __restrict__ h, int N) {
    const int slot = blockIdx.z;
    long idx = (long)blockIdx.x * blockDim.x + threadIdx.x;
    if (idx >= (long)N * HID) return;
    const int n = (int)(idx >> 7), c = (int)(idx & 127);
    const float* x = (slot < 2) ? dx : sx;
    const float* W = aW + (size_t)slot * 9 * HID;
    float acc = ab[slot * HID + c];
#pragma unroll
    for (int k = 0; k < 9; k++) acc = fmaf(x[n * 9 + k], W[k * HID + c], acc);
    h[(size_t)slot * N * HID + idx] = f2bf(acc);
}

// ---------------------------------------------------------------------------
// Fused GIN layer WITH inline gather:
//   z[n] = (1+eps)*h[n] + sum h[src]   (gathered straight into LDS, bf16)
//   h_out = relu(BN2( relu(BN1(z@W1+b1)) @ W2 + b2 ))
// Block 256 thr = 4 waves; 128 rows/block. LDS 128x136 u16 reused z -> z2.
// MFMA 16x16x32 bf16, C/D: col=lane&15, row=(lane>>4)*4+reg [m89-verified].
// ---------------------------------------------------------------------------
__global__ __launch_bounds__(256, 2) void fused_layer(
    const int* __restrict__ rpd, const int* __restrict__ sid,
    const int* __restrict__ rps, const int* __restrict__ sis,
    const u16* __restrict__ h,
    const u16* __restrict__ W1t, const u16* __restrict__ W2t,
    const float* __restrict__ b1, const float* __restrict__ g1, const float* __restrict__ be1,
    const float* __restrict__ m1, const float* __restrict__ v1,
    const float* __restrict__ b2, const float* __restrict__ g2, const float* __restrict__ be2,
    const float* __restrict__ m2, const float* __restrict__ v2,
    const float* __restrict__ eps,
    u16* __restrict__ out, int M, int l) {

    const int slot = blockIdx.z;
    const int m0 = blockIdx.x * 128;
    const int el = slot * NLAYER + l;
    const u16* Wp1 = W1t + (size_t)el * (256 * 128);
    const u16* Wp2 = W2t + (size_t)el * (128 * 256);
    const size_t poff1 = (size_t)el * 256;
    const size_t poff2 = (size_t)el * 128;
    const int* rowptr = (slot < 2) ? rpd : rps;
    const int* srcidx = (slot < 2) ? sid : sis;
    const u16* hp = h + (size_t)slot * M * 128;

    __shared__ u16 sm[128 * 136];  // 34.8 KB, z tile then z2 halves

    const int tid = threadIdx.x;
    const int lane = tid & 63;
    const int w = tid >> 6;
    const int sl = lane & 15;
    const int k8 = lane >> 4;
    const int subbase = lane & 48;

    // ---- gather z tile directly into LDS (16 nodes per pass, 16 lanes/node) ----
    {
        const float scale = 1.f + eps[slot * NLAYER + l];
        const int coff = sl * 8;
#pragma unroll
        for (int pass = 0; pass < 8; pass++) {
            const int row = pass * 16 + (tid >> 4);
            int node = m0 + row; if (node >= M) node = M - 1;
            const int lo = rowptr[node], hi = rowptr[node + 1];
            u16x8 hv = *(const u16x8*)(hp + (size_t)node * 128 + coff);
            float s[8];
#pragma unroll
            for (int i = 0; i < 8; i++) s[i] = bf2f(hv[i]) * scale;
            for (int base = lo; base < hi; base += 16) {
                const int cnt = min(16, hi - base);
                int idx = (sl < cnt) ? srcidx[base + sl] : 0;
                int j = 0;
                for (; j + 4 <= cnt; j += 4) {
                    const int s0 = __shfl(idx, subbase + j);
                    const int s1 = __shfl(idx, subbase + j + 1);
                    const int s2 = __shfl(idx, subbase + j + 2);
                    const int s3 = __shfl(idx, subbase + j + 3);
                    u16x8 v0 = *(const u16x8*)(hp + (size_t)s0 * 128 + coff);
                    u16x8 v1 = *(const u16x8*)(hp + (size_t)s1 * 128 + coff);
                    u16x8 v2 = *(const u16x8*)(hp + (size_t)s2 * 128 + coff);
                    u16x8 v3 = *(const u16x8*)(hp + (size_t)s3 * 128 + coff);
#pragma unroll
                    for (int i = 0; i < 8; i++)
                        s[i] += (bf2f(v0[i]) + bf2f(v1[i])) + (bf2f(v2[i]) + bf2f(v3[i]));
                }
                for (; j < cnt; j++) {
                    const int sj = __shfl(idx, subbase + j);
                    u16x8 v = *(const u16x8*)(hp + (size_t)sj * 128 + coff);
#pragma unroll
                    for (int i = 0; i < 8; i++) s[i] += bf2f(v[i]);
                }
            }
            u16x8 o;
#pragma unroll
            for (int i = 0; i < 8; i++) o[i] = f2bf(s[i]);
            *(u16x8*)&sm[row * 136 + coff] = o;
        }
    }
    __syncthreads();

    // ---- GEMM1: 128 x 256, K=128 ----
    floatx4 acc1[8][4];
#pragma unroll
    for (int mt = 0; mt < 8; mt++)
#pragma unroll
        for (int c = 0; c < 4; c++) acc1[mt][c] = (floatx4)0.f;

#pragma unroll
    for (int ks = 0; ks < 4; ks++) {
        short8 a[8], b[4];
#pragma unroll
        for (int mt = 0; mt < 8; mt++)
            a[mt] = *(const short8*)&sm[(mt * 16 + sl) * 136 + ks * 32 + k8 * 8];
#pragma unroll
        for (int c = 0; c < 4; c++) {
            const int n = (c * 4 + w) * 16 + sl;
            b[c] = *(const short8*)(Wp1 + (size_t)n * 128 + ks * 32 + k8 * 8);
        }
#pragma unroll
        for (int mt = 0; mt < 8; mt++)
#pragma unroll
            for (int c = 0; c < 4; c++)
                acc1[mt][c] = __builtin_amdgcn_mfma_f32_16x16x32_bf16(a[mt], b[c], acc1[mt][c], 0, 0, 0);
    }
    __syncthreads();  // all waves done reading z tile

    // ---- z2 halves + GEMM2 ----
    const int wr = w & 1, wc = w >> 1;
    floatx4 acc2[4][4];
#pragma unroll
    for (int mt = 0; mt < 4; mt++)
#pragma unroll
        for (int nt = 0; nt < 4; nt++) acc2[mt][nt] = (floatx4)0.f;

#pragma unroll
    for (int part = 0; part < 2; part++) {
#pragma unroll
        for (int c = part * 2; c < part * 2 + 2; c++) {
            const int gcol = (c * 4 + w) * 16 + sl;
            const int lcol = gcol - part * 128;
            const float sc = g1[poff1 + gcol] * rsqrtf(v1[poff1 + gcol] + 1e-5f);
            const float sh = (b1[poff1 + gcol] - m1[poff1 + gcol]) * sc + be1[poff1 + gcol];
#pragma unroll
            for (int mt = 0; mt < 8; mt++) {
#pragma unroll
                for (int r = 0; r < 4; r++) {
                    const int m = mt * 16 + k8 * 4 + r;
                    sm[m * 136 + lcol] = f2bf(fmaxf(fmaf(acc1[mt][c][r], sc, sh), 0.f));
                }
            }
        }
        __syncthreads();
#pragma unroll
        for (int ks = 0; ks < 4; ks++) {
            short8 a[4], b[4];
#pragma unroll
            for (int mt = 0; mt < 4; mt++)
                a[mt] = *(const short8*)&sm[(wr * 64 + mt * 16 + sl) * 136 + ks * 32 + k8 * 8];
#pragma unroll
            for (int nt = 0; nt < 4; nt++) {
                const int n = wc * 64 + nt * 16 + sl;
                b[nt] = *(const short8*)(Wp2 + (size_t)n * 256 + part * 128 + ks * 32 + k8 * 8);
            }
#pragma unroll
            for (int mt = 0; mt < 4; mt++)
#pragma unroll
                for (int nt = 0; nt < 4; nt++)
                    acc2[mt][nt] = __builtin_amdgcn_mfma_f32_16x16x32_bf16(a[mt], b[nt], acc2[mt][nt], 0, 0, 0);
        }
        if (part == 0) __syncthreads();
    }

    // ---- BN2 + ReLU epilogue ----
    u16* outp = out + (size_t)slot * M * 128;
#pragma unroll
    for (int nt = 0; nt < 4; nt++) {
        const int col = wc * 64 + nt * 16 + sl;
        const float sc = g2[poff2 + col] * rsqrtf(v2[poff2 + col] + 1e-5f);
        const float sh = (b2[poff2 + col] - m2[poff2 + col]) * sc + be2[poff2 + col];
#pragma unroll
        for (int mt = 0; mt < 4; mt++) {
#pragma unroll
            for (int r = 0; r < 4; r++) {
                const int gr = m0 + wr * 64 + mt * 16 + k8 * 4 + r;
                if (gr < M)
                    outp[(size_t)gr * 128 + col] = f2bf(fmaxf(fmaf(acc2[mt][nt][r], sc, sh), 0.f));
            }
        }
    }
}

// ---------------------------------------------------------------------------
// Segment-mean pool (bat sorted). bf16 in, fp32 out.
// ---------------------------------------------------------------------------
__global__ __launch_bounds__(128) void pool_kernel(const int* __restrict__ db,
                                                   const int* __restrict__ sb,
                                                   const u16* __restrict__ h,
                                                   float* __restrict__ emb,
                                                   int N, int B) {
    const int slot = blockIdx.z;
    const int* bat = (slot < 2) ? db : sb;
    const int g = blockIdx.x;
    const int lo = lowbound(bat, N, g);
    const int hi = lowbound(bat, N, g + 1);
    const int c = threadIdx.x;
    float s = 0.f;
    const u16* hp = h + (size_t)slot * N * HID;
    for (int n = lo; n < hi; n++) s += bf2f(hp[(size_t)n * HID + c]);
    const float cnt = (float)(hi - lo);
    emb[((size_t)slot * B + g) * HID + c] = s / fmaxf(cnt, 1.f);
}

// ---------------------------------------------------------------------------
__device__ __forceinline__ float block_sum128(float x, float* red, int tid) {
    red[tid] = x;
    __syncthreads();
    if (tid < 64) {
        float v = red[tid] + red[tid + 64];
#pragma unroll
        for (int o = 32; o > 0; o >>= 1) v += __shfl_down(v, o);
        if (tid == 0) red[0] = v;
    }
    __syncthreads();
    float r = red[0];
    __syncthreads();
    return r;
}

// ---------------------------------------------------------------------------
// Fusion head (fp32)
// ---------------------------------------------------------------------------
__global__ __launch_bounds__(128) void fusion_kernel(
    const float* __restrict__ emb, const float* __restrict__ t,
    const float* __restrict__ tW1, const float* __restrict__ tb1,
    const float* __restrict__ tW2, const float* __restrict__ tb2,
    const float* __restrict__ iW, const float* __restrict__ ib,
    const float* __restrict__ ilg, const float* __restrict__ ilb,
    const float* __restrict__ fW1, const float* __restrict__ fb1,
    const float* __restrict__ l1g, const float* __restrict__ l1b,
    const float* __restrict__ fW2, const float* __restrict__ fb2,
    const float* __restrict__ l2g, const float* __restrict__ l2b,
    const float* __restrict__ fW3, const float* __restrict__ fb3,
    float* __restrict__ out, int B) {
    const int r = blockIdx.x;
    const int tid = threadIdx.x;
    __shared__ float cs[256];
    __shared__ float cat[288];
    __shared__ float buf[128];
    __shared__ float red[128];
    __shared__ float tmp32[32];

    cs[tid]        = emb[((size_t)1 * B + r) * HID + tid];
    cs[128 + tid]  = emb[((size_t)2 * B + r) * HID + tid];
    cat[tid]       = emb[((size_t)0 * B + r) * HID + tid];
    __syncthreads();

    float acc = ib[tid];
    for (int k = 0; k < 256; k++) acc = fmaf(cs[k], iW[k * HID + tid], acc);
    float mu  = block_sum128(acc, red, tid) * (1.f / 128.f);
    float d   = acc - mu;
    float var = block_sum128(d * d, red, tid) * (1.f / 128.f);
    float inter = fmaxf(d * rsqrtf(var + 1e-5f) * ilg[tid] + ilb[tid], 0.f);
    cat[128 + tid] = inter;

    if (tid < 32) tmp32[tid] = fmaxf(fmaf(t[r], tW1[tid], tb1[tid]), 0.f);
    __syncthreads();
    if (tid < 32) {
        float a2 = tb2[tid];
        for (int j = 0; j < 32; j++) a2 = fmaf(tmp32[j], tW2[j * 32 + tid], a2);
        cat[256 + tid] = a2;
    }
    __syncthreads();

    float a1 = fb1[tid];
    for (int k = 0; k < 288; k++) a1 = fmaf(cat[k], fW1[k * HID + tid], a1);
    mu  = block_sum128(a1, red, tid) * (1.f / 128.f);
    d   = a1 - mu;
    var = block_sum128(d * d, red, tid) * (1.f / 128.f);
    buf[tid] = fmaxf(d * rsqrtf(var + 1e-5f) * l1g[tid] + l1b[tid], 0.f);
    __syncthreads();

    float a2v = 0.f;
    if (tid < 64) {
        a2v = fb2[tid];
        for (int k = 0; k < 128; k++) a2v = fmaf(buf[k], fW2[k * 64 + tid], a2v);
    }
    mu = block_sum128((tid < 64) ? a2v : 0.f, red, tid) * (1.f / 64.f);
    float d2 = (tid < 64) ? (a2v - mu) : 0.f;
    var = block_sum128(d2 * d2, red, tid) * (1.f / 64.f);
    float contrib = 0.f;
    if (tid < 64) {
        float h2 = fmaxf(d2 * rsqrtf(var + 1e-5f) * l2g[tid] + l2b[tid], 0.f);
        contrib = h2 * fW3[tid];
    }
    float s = block_sum128(contrib, red, tid);
    if (tid == 0) out[r] = s + fb3[0];
}

// ---------------------------------------------------------------------------
extern "C" void kernel_launch(void* const* d_in, const int* in_sizes, int n_in,
                              void* d_out, int out_size, void* d_ws, size_t ws_size,
                              hipStream_t stream) {
    const float* dx  = (const float*)d_in[0];
    const int*   de  = (const int*)d_in[1];
    const int*   db  = (const int*)d_in[2];
    const float* sx  = (const float*)d_in[3];
    const int*   se  = (const int*)d_in[4];
    const int*   sb  = (const int*)d_in[5];
    const float* t   = (const float*)d_in[6];
    const float* aW  = (const float*)d_in[7];
    const float* ab  = (const float*)d_in[8];
    const float* eps = (const float*)d_in[9];
    const float* W1  = (const float*)d_in[10];
    const float* b1  = (const float*)d_in[11];
    const float* g1  = (const float*)d_in[12];
    const float* be1 = (const float*)d_in[13];
    const float* m1  = (const float*)d_in[14];
    const float* v1  = (const float*)d_in[15];
    const float* W2  = (const float*)d_in[16];
    const float* b2  = (const float*)d_in[17];
    const float* g2  = (const float*)d_in[18];
    const float* be2 = (const float*)d_in[19];
    const float* m2  = (const float*)d_in[20];
    const float* v2  = (const float*)d_in[21];
    const float* tW1 = (const float*)d_in[22];
    const float* tb1 = (const float*)d_in[23];
    const float* tW2 = (const float*)d_in[24];
    const float* tb2 = (const float*)d_in[25];
    const float* iW  = (const float*)d_in[26];
    const float* ib  = (const float*)d_in[27];
    const float* ilg = (const float*)d_in[28];
    const float* ilb = (const float*)d_in[29];
    const float* fW1 = (const float*)d_in[30];
    const float* fb1 = (const float*)d_in[31];
    const float* l1g = (const float*)d_in[32];
    const float* l1b = (const float*)d_in[33];
    const float* fW2 = (const float*)d_in[34];
    const float* fb2 = (const float*)d_in[35];
    const float* l2g = (const float*)d_in[36];
    const float* l2b = (const float*)d_in[37];
    const float* fW3 = (const float*)d_in[38];
    const float* fb3 = (const float*)d_in[39];
    float* out = (float*)d_out;

    const int N  = in_sizes[0] / 9;
    const int Ed = in_sizes[1] / 2;
    const int Es = in_sizes[4] / 2;
    const int B  = in_sizes[6];
    const int NBU = (N + 63) >> 6;           // buckets of 64 nodes (<=1024 for N<=65536)
    const int Emax = (Ed > Es) ? Ed : Es;

    // ---- workspace layout ----
    char* w8 = (char*)d_ws;
    int* rpd   = (int*)w8;                   // [N+1]
    int* rps   = rpd + (N + 1);              // [N+1]
    int* bcnt  = rps + (N + 1);              // [2*NBU]
    int* bpos  = bcnt + 2 * NBU;             // [2*NBU]  (memset with bcnt)
    int* bbase = bpos + 2 * NBU;             // [2*(NBU+1)]
    int* sid   = bbase + 2 * (NBU + 1);      // [Ed]
    int* sis   = sid + Ed;                   // [Es]
    uintptr_t ealign = (((uintptr_t)(sis + Es)) + 15) & ~(uintptr_t)15;
    int2* ebufd = (int2*)ealign;             // [Ed]
    int2* ebufs = ebufd + Ed;                // [Es]
    uintptr_t foff = (((uintptr_t)(ebufs + Es)) + 255) & ~(uintptr_t)255;

    const int WT = 3 * NLAYER * 128 * 256;
    u16* W1t = (u16*)foff;
    u16* W2t = W1t + WT;
    const size_t hS = (size_t)N * HID;
    u16* hbuf = W2t + WT;
    float* emb = (float*)(((uintptr_t)(hbuf + 3 * hS) + 255) & ~(uintptr_t)255);

    // ---- weight prep + CSR build v2 ----
    prep_weights<<<(2 * WT + 255) / 256, 256, 0, stream>>>(W1, W2, W1t, W2t);
    hipMemsetAsync(bcnt, 0, (size_t)4 * NBU * sizeof(int), stream);  // bcnt + bpos
    {
        dim3 ge((Emax + 255) / 256, 2);
        countA<<<ge, 256, 0, stream>>>(de, se, bcnt, Ed, Es, NBU);
        scanB<<<2, 1024, 0, stream>>>(bcnt, bbase, NBU);
        scatterA<<<ge, 256, 0, stream>>>(de, se, bbase, bpos, ebufd, ebufs, Ed, Es, NBU);
        dim3 gb(NBU, 2);
        passB<<<gb, 256, 0, stream>>>(ebufd, ebufs, bbase, rpd, rps, sid, sis, N, NBU);
    }

    // ---- encoders (3 slots batched via grid.z) ----
    {
        dim3 ga((N * HID + 255) / 256, 1, 3);
        atom_kernel<<<ga, 256, 0, stream>>>(dx, sx, aW, ab, hbuf, N);
        for (int l = 0; l < NLAYER; l++) {
            dim3 gf((N + 127) / 128, 1, 3);
            fused_layer<<<gf, 256, 0, stream>>>(rpd, sid, rps, sis, hbuf, W1t, W2t,
                                                b1, g1, be1, m1, v1,
                                                b2, g2, be2, m2, v2,
                                                eps, hbuf, N, l);
        }
        dim3 gp(B, 1, 3);
        pool_kernel<<<gp, 128, 0, stream>>>(db, sb, hbuf, emb, N, B);
    }
    fusion_kernel<<<B, 128, 0, stream>>>(emb, t, tW1, tb1, tW2, tb2,
                                         iW, ib, ilg, ilb, fW1, fb1, l1g, l1b,
                                         fW2, fb2, l2g, l2b, fW3, fb3, out, B);
}

// Round 7
// 971.385 us; speedup vs baseline: 1.3598x; 1.3598x over previous
//
#include <hip/hip_runtime.h>

#define HID 128
#define NLAYER 4

typedef unsigned short u16;
typedef __attribute__((ext_vector_type(8))) unsigned short u16x8;
typedef __attribute__((ext_vector_type(8))) short short8;
typedef __attribute__((ext_vector_type(4))) float floatx4;

__device__ __forceinline__ float bf2f(u16 u) {
    union { unsigned int i; float f; } v; v.i = ((unsigned int)u) << 16; return v.f;
}
__device__ __forceinline__ u16 f2bf(float f) {
    union { float f; unsigned int i; } v; v.f = f;
    unsigned int r = v.i + 0x7FFFu + ((v.i >> 16) & 1u);
    return (u16)(r >> 16);
}

// ---------------------------------------------------------------------------
__device__ __forceinline__ int lowbound(const int* __restrict__ a, int n, int v) {
    int lo = 0, hi = n;
    while (lo < hi) {
        int mid = (lo + hi) >> 1;
        if (a[mid] < v) lo = mid + 1; else hi = mid;
    }
    return lo;
}

// ---------------------------------------------------------------------------
// Weight prep: fp32 -> bf16, transposed to [enc][l][n][k].
// ---------------------------------------------------------------------------
__global__ void prep_weights(const float* __restrict__ W1, const float* __restrict__ W2,
                             u16* __restrict__ W1t, u16* __restrict__ W2t) {
    const int T = 3 * NLAYER * 128 * 256;  // 393216
    int o = blockIdx.x * blockDim.x + threadIdx.x;
    if (o < T) {
        int k = o & 127, n = (o >> 7) & 255, el = o >> 15;
        W1t[o] = f2bf(W1[((size_t)el * 128 + k) * 256 + n]);
    } else if (o < 2 * T) {
        int o2 = o - T;
        int k = o2 & 255, n = (o2 >> 8) & 127, el = o2 >> 15;
        W2t[o2] = f2bf(W2[((size_t)el * 256 + k) * 128 + n]);
    }
}

// ---------------------------------------------------------------------------
// CSR build (R3 chain, per-node atomics: 50k counters -> ~12 ops/counter, low
// contention; bucket-grained counters (R4) serialized at ~767 ops/counter).
// ---------------------------------------------------------------------------
__global__ void hist2(const int* __restrict__ de, const int* __restrict__ se,
                      int* __restrict__ cntd, int* __restrict__ cnts, int Ed, int Es) {
    const int g = blockIdx.y;
    const int* ei = g ? se : de;
    int* cnt = g ? cnts : cntd;
    const int E = g ? Es : Ed;
    int e = blockIdx.x * 256 + threadIdx.x;
    if (e < E) atomicAdd(&cnt[ei[E + e]], 1);
}

__global__ __launch_bounds__(256) void scan1v(const int* __restrict__ cntd,
                                              const int* __restrict__ cnts,
                                              int* __restrict__ bsumd,
                                              int* __restrict__ bsums, int N) {
    const int g = blockIdx.y;
    const int* cnt = g ? cnts : cntd;
    int* bsum = g ? bsums : bsumd;
    __shared__ int s[256];
    int i = blockIdx.x * 256 + threadIdx.x;
    s[threadIdx.x] = (i < N) ? cnt[i] : 0;
    __syncthreads();
    for (int o = 128; o > 0; o >>= 1) {
        if (threadIdx.x < o) s[threadIdx.x] += s[threadIdx.x + o];
        __syncthreads();
    }
    if (threadIdx.x == 0) bsum[blockIdx.x] = s[0];
}

__global__ __launch_bounds__(256) void scan2v(int* __restrict__ bsumd,
                                              int* __restrict__ bsums, int nb) {
    int* bsum = blockIdx.x ? bsums : bsumd;
    __shared__ int s[256];
    __shared__ int carry;
    if (threadIdx.x == 0) carry = 0;
    __syncthreads();
    for (int base = 0; base < nb; base += 256) {
        int i = base + threadIdx.x;
        int v = (i < nb) ? bsum[i] : 0;
        s[threadIdx.x] = v;
        __syncthreads();
        for (int o = 1; o < 256; o <<= 1) {
            int tv = (threadIdx.x >= o) ? s[threadIdx.x - o] : 0;
            __syncthreads();
            s[threadIdx.x] += tv;
            __syncthreads();
        }
        int excl = carry + s[threadIdx.x] - v;
        if (i < nb) bsum[i] = excl;
        __syncthreads();
        if (threadIdx.x == 0) carry += s[255];
        __syncthreads();
    }
}

__global__ __launch_bounds__(256) void scan3v(const int* __restrict__ cntd,
                                              const int* __restrict__ cnts,
                                              const int* __restrict__ bsumd,
                                              const int* __restrict__ bsums,
                                              int* __restrict__ rpd, int* __restrict__ rps,
                                              int N, int Ed, int Es) {
    const int g = blockIdx.y;
    const int* cnt = g ? cnts : cntd;
    const int* bsum = g ? bsums : bsumd;
    int* rowptr = g ? rps : rpd;
    const int E = g ? Es : Ed;
    __shared__ int s[256];
    int i = blockIdx.x * 256 + threadIdx.x;
    int v = (i < N) ? cnt[i] : 0;
    s[threadIdx.x] = v;
    __syncthreads();
    for (int o = 1; o < 256; o <<= 1) {
        int tv = (threadIdx.x >= o) ? s[threadIdx.x - o] : 0;
        __syncthreads();
        s[threadIdx.x] += tv;
        __syncthreads();
    }
    if (i < N) rowptr[i] = bsum[blockIdx.x] + s[threadIdx.x] - v;
    if (i == 0 && blockIdx.x == 0) rowptr[N] = E;
}

__global__ void fill2(const int* __restrict__ de, const int* __restrict__ se,
                      const int* __restrict__ rpd, const int* __restrict__ rps,
                      int* __restrict__ cnt2d, int* __restrict__ cnt2s,
                      int* __restrict__ sid, int* __restrict__ sis, int Ed, int Es) {
    const int g = blockIdx.y;
    const int* ei = g ? se : de;
    const int* rowptr = g ? rps : rpd;
    int* cnt2 = g ? cnt2s : cnt2d;
    int* srcidx = g ? sis : sid;
    const int E = g ? Es : Ed;
    int e = blockIdx.x * 256 + threadIdx.x;
    if (e < E) {
        const int dst = ei[E + e];
        const int pos = rowptr[dst] + atomicAdd(&cnt2[dst], 1);
        srcidx[pos] = ei[e];
    }
}

// ---------------------------------------------------------------------------
// Atom encoder: h = x @ aW + ab  (fp32 compute, bf16 store). grid.z = slot.
// ---------------------------------------------------------------------------
__global__ void atom_kernel(const float* __restrict__ dx, const float* __restrict__ sx,
                            const float* __restrict__ aW, const float* __restrict__ ab,
                            u16* __restrict__ h, int N) {
    const int slot = blockIdx.z;
    long idx = (long)blockIdx.x * blockDim.x + threadIdx.x;
    if (idx >= (long)N * HID) return;
    const int n = (int)(idx >> 7), c = (int)(idx & 127);
    const float* x = (slot < 2) ? dx : sx;
    const float* W = aW + (size_t)slot * 9 * HID;
    float acc = ab[slot * HID + c];
#pragma unroll
    for (int k = 0; k < 9; k++) acc = fmaf(x[n * 9 + k], W[k * HID + c], acc);
    h[(size_t)slot * N * HID + idx] = f2bf(acc);
}

// ---------------------------------------------------------------------------
// Fused GIN layer WITH inline gather:
//   z[n] = (1+eps)*h[n] + sum h[src]   (gathered straight into LDS, bf16)
//   h_out = relu(BN2( relu(BN1(z@W1+b1)) @ W2 + b2 ))
// Block 256 thr = 4 waves; 128 rows/block. LDS 128x136 u16 reused z -> z2.
// MFMA 16x16x32 bf16, C/D: col=lane&15, row=(lane>>4)*4+reg [m89-verified].
// ---------------------------------------------------------------------------
__global__ __launch_bounds__(256, 2) void fused_layer(
    const int* __restrict__ rpd, const int* __restrict__ sid,
    const int* __restrict__ rps, const int* __restrict__ sis,
    const u16* __restrict__ h,
    const u16* __restrict__ W1t, const u16* __restrict__ W2t,
    const float* __restrict__ b1, const float* __restrict__ g1, const float* __restrict__ be1,
    const float* __restrict__ m1, const float* __restrict__ v1,
    const float* __restrict__ b2, const float* __restrict__ g2, const float* __restrict__ be2,
    const float* __restrict__ m2, const float* __restrict__ v2,
    const float* __restrict__ eps,
    u16* __restrict__ out, int M, int l) {

    const int slot = blockIdx.z;
    const int m0 = blockIdx.x * 128;
    const int el = slot * NLAYER + l;
    const u16* Wp1 = W1t + (size_t)el * (256 * 128);
    const u16* Wp2 = W2t + (size_t)el * (128 * 256);
    const size_t poff1 = (size_t)el * 256;
    const size_t poff2 = (size_t)el * 128;
    const int* rowptr = (slot < 2) ? rpd : rps;
    const int* srcidx = (slot < 2) ? sid : sis;
    const u16* hp = h + (size_t)slot * M * 128;

    __shared__ u16 sm[128 * 136];  // 34.8 KB, z tile then z2 halves

    const int tid = threadIdx.x;
    const int lane = tid & 63;
    const int w = tid >> 6;
    const int sl = lane & 15;
    const int k8 = lane >> 4;
    const int subbase = lane & 48;

    // ---- gather z tile directly into LDS (16 nodes per pass, 16 lanes/node) ----
    {
        const float scale = 1.f + eps[slot * NLAYER + l];
        const int coff = sl * 8;
#pragma unroll
        for (int pass = 0; pass < 8; pass++) {
            const int row = pass * 16 + (tid >> 4);
            int node = m0 + row; if (node >= M) node = M - 1;
            const int lo = rowptr[node], hi = rowptr[node + 1];
            u16x8 hv = *(const u16x8*)(hp + (size_t)node * 128 + coff);
            float s[8];
#pragma unroll
            for (int i = 0; i < 8; i++) s[i] = bf2f(hv[i]) * scale;
            for (int base = lo; base < hi; base += 16) {
                const int cnt = min(16, hi - base);
                int idx = (sl < cnt) ? srcidx[base + sl] : 0;
                int j = 0;
                for (; j + 4 <= cnt; j += 4) {
                    const int s0 = __shfl(idx, subbase + j);
                    const int s1 = __shfl(idx, subbase + j + 1);
                    const int s2 = __shfl(idx, subbase + j + 2);
                    const int s3 = __shfl(idx, subbase + j + 3);
                    u16x8 v0 = *(const u16x8*)(hp + (size_t)s0 * 128 + coff);
                    u16x8 v1 = *(const u16x8*)(hp + (size_t)s1 * 128 + coff);
                    u16x8 v2 = *(const u16x8*)(hp + (size_t)s2 * 128 + coff);
                    u16x8 v3 = *(const u16x8*)(hp + (size_t)s3 * 128 + coff);
#pragma unroll
                    for (int i = 0; i < 8; i++)
                        s[i] += (bf2f(v0[i]) + bf2f(v1[i])) + (bf2f(v2[i]) + bf2f(v3[i]));
                }
                for (; j < cnt; j++) {
                    const int sj = __shfl(idx, subbase + j);
                    u16x8 v = *(const u16x8*)(hp + (size_t)sj * 128 + coff);
#pragma unroll
                    for (int i = 0; i < 8; i++) s[i] += bf2f(v[i]);
                }
            }
            u16x8 o;
#pragma unroll
            for (int i = 0; i < 8; i++) o[i] = f2bf(s[i]);
            *(u16x8*)&sm[row * 136 + coff] = o;
        }
    }
    __syncthreads();

    // ---- GEMM1: 128 x 256, K=128 ----
    floatx4 acc1[8][4];
#pragma unroll
    for (int mt = 0; mt < 8; mt++)
#pragma unroll
        for (int c = 0; c < 4; c++) acc1[mt][c] = (floatx4)0.f;

#pragma unroll
    for (int ks = 0; ks < 4; ks++) {
        short8 a[8], b[4];
#pragma unroll
        for (int mt = 0; mt < 8; mt++)
            a[mt] = *(const short8*)&sm[(mt * 16 + sl) * 136 + ks * 32 + k8 * 8];
#pragma unroll
        for (int c = 0; c < 4; c++) {
            const int n = (c * 4 + w) * 16 + sl;
            b[c] = *(const short8*)(Wp1 + (size_t)n * 128 + ks * 32 + k8 * 8);
        }
#pragma unroll
        for (int mt = 0; mt < 8; mt++)
#pragma unroll
            for (int c = 0; c < 4; c++)
                acc1[mt][c] = __builtin_amdgcn_mfma_f32_16x16x32_bf16(a[mt], b[c], acc1[mt][c], 0, 0, 0);
    }
    __syncthreads();  // all waves done reading z tile

    // ---- z2 halves + GEMM2 ----
    const int wr = w & 1, wc = w >> 1;
    floatx4 acc2[4][4];
#pragma unroll
    for (int mt = 0; mt < 4; mt++)
#pragma unroll
        for (int nt = 0; nt < 4; nt++) acc2[mt][nt] = (floatx4)0.f;

#pragma unroll
    for (int part = 0; part < 2; part++) {
#pragma unroll
        for (int c = part * 2; c < part * 2 + 2; c++) {
            const int gcol = (c * 4 + w) * 16 + sl;
            const int lcol = gcol - part * 128;
            const float sc = g1[poff1 + gcol] * rsqrtf(v1[poff1 + gcol] + 1e-5f);
            const float sh = (b1[poff1 + gcol] - m1[poff1 + gcol]) * sc + be1[poff1 + gcol];
#pragma unroll
            for (int mt = 0; mt < 8; mt++) {
#pragma unroll
                for (int r = 0; r < 4; r++) {
                    const int m = mt * 16 + k8 * 4 + r;
                    sm[m * 136 + lcol] = f2bf(fmaxf(fmaf(acc1[mt][c][r], sc, sh), 0.f));
                }
            }
        }
        __syncthreads();
#pragma unroll
        for (int ks = 0; ks < 4; ks++) {
            short8 a[4], b[4];
#pragma unroll
            for (int mt = 0; mt < 4; mt++)
                a[mt] = *(const short8*)&sm[(wr * 64 + mt * 16 + sl) * 136 + ks * 32 + k8 * 8];
#pragma unroll
            for (int nt = 0; nt < 4; nt++) {
                const int n = wc * 64 + nt * 16 + sl;
                b[nt] = *(const short8*)(Wp2 + (size_t)n * 256 + part * 128 + ks * 32 + k8 * 8);
            }
#pragma unroll
            for (int mt = 0; mt < 4; mt++)
#pragma unroll
                for (int nt = 0; nt < 4; nt++)
                    acc2[mt][nt] = __builtin_amdgcn_mfma_f32_16x16x32_bf16(a[mt], b[nt], acc2[mt][nt], 0, 0, 0);
        }
        if (part == 0) __syncthreads();
    }

    // ---- BN2 + ReLU epilogue ----
    u16* outp = out + (size_t)slot * M * 128;
#pragma unroll
    for (int nt = 0; nt < 4; nt++) {
        const int col = wc * 64 + nt * 16 + sl;
        const float sc = g2[poff2 + col] * rsqrtf(v2[poff2 + col] + 1e-5f);
        const float sh = (b2[poff2 + col] - m2[poff2 + col]) * sc + be2[poff2 + col];
#pragma unroll
        for (int mt = 0; mt < 4; mt++) {
#pragma unroll
            for (int r = 0; r < 4; r++) {
                const int gr = m0 + wr * 64 + mt * 16 + k8 * 4 + r;
                if (gr < M)
                    outp[(size_t)gr * 128 + col] = f2bf(fmaxf(fmaf(acc2[mt][nt][r], sc, sh), 0.f));
            }
        }
    }
}

// ---------------------------------------------------------------------------
// Segment-mean pool (bat sorted). bf16 in, fp32 out.
// ---------------------------------------------------------------------------
__global__ __launch_bounds__(128) void pool_kernel(const int* __restrict__ db,
                                                   const int* __restrict__ sb,
                                                   const u16* __restrict__ h,
                                                   float* __restrict__ emb,
                                                   int N, int B) {
    const int slot = blockIdx.z;
    const int* bat = (slot < 2) ? db : sb;
    const int g = blockIdx.x;
    const int lo = lowbound(bat, N, g);
    const int hi = lowbound(bat, N, g + 1);
    const int c = threadIdx.x;
    float s = 0.f;
    const u16* hp = h + (size_t)slot * N * HID;
    for (int n = lo; n < hi; n++) s += bf2f(hp[(size_t)n * HID + c]);
    const float cnt = (float)(hi - lo);
    emb[((size_t)slot * B + g) * HID + c] = s / fmaxf(cnt, 1.f);
}

// ---------------------------------------------------------------------------
__device__ __forceinline__ float block_sum128(float x, float* red, int tid) {
    red[tid] = x;
    __syncthreads();
    if (tid < 64) {
        float v = red[tid] + red[tid + 64];
#pragma unroll
        for (int o = 32; o > 0; o >>= 1) v += __shfl_down(v, o);
        if (tid == 0) red[0] = v;
    }
    __syncthreads();
    float r = red[0];
    __syncthreads();
    return r;
}

// ---------------------------------------------------------------------------
// Fusion head, 4 rows per block: weight element loaded once, FMA'd into 4
// row-accumulators (4x less L2 weight traffic). Final 64-wide LNs use
// wave-local shfl reductions.
// ---------------------------------------------------------------------------
__global__ __launch_bounds__(128) void fusion_kernel(
    const float* __restrict__ emb, const float* __restrict__ t,
    const float* __restrict__ tW1, const float* __restrict__ tb1,
    const float* __restrict__ tW2, const float* __restrict__ tb2,
    const float* __restrict__ iW, const float* __restrict__ ib,
    const float* __restrict__ ilg, const float* __restrict__ ilb,
    const float* __restrict__ fW1, const float* __restrict__ fb1,
    const float* __restrict__ l1g, const float* __restrict__ l1b,
    const float* __restrict__ fW2, const float* __restrict__ fb2,
    const float* __restrict__ l2g, const float* __restrict__ l2b,
    const float* __restrict__ fW3, const float* __restrict__ fb3,
    float* __restrict__ out, int B) {
    const int r0 = blockIdx.x * 4;
    const int tid = threadIdx.x;
    __shared__ float cs[4][256];
    __shared__ float cat[4][288];
    __shared__ float buf[4][128];
    __shared__ float red[128];
    __shared__ float tmp[4][32];

#pragma unroll
    for (int j = 0; j < 4; j++) {
        const int r = min(r0 + j, B - 1);
        cs[j][tid]       = emb[((size_t)1 * B + r) * HID + tid];
        cs[j][128 + tid] = emb[((size_t)2 * B + r) * HID + tid];
        cat[j][tid]      = emb[((size_t)0 * B + r) * HID + tid];
    }
    __syncthreads();

    // inter = relu(LN(cs @ iW + ib))
    float acc[4];
#pragma unroll
    for (int j = 0; j < 4; j++) acc[j] = ib[tid];
    for (int k = 0; k < 256; k++) {
        const float wv = iW[k * HID + tid];
#pragma unroll
        for (int j = 0; j < 4; j++) acc[j] = fmaf(cs[j][k], wv, acc[j]);
    }
#pragma unroll
    for (int j = 0; j < 4; j++) {
        float mu  = block_sum128(acc[j], red, tid) * (1.f / 128.f);
        float d   = acc[j] - mu;
        float var = block_sum128(d * d, red, tid) * (1.f / 128.f);
        cat[j][128 + tid] = fmaxf(d * rsqrtf(var + 1e-5f) * ilg[tid] + ilb[tid], 0.f);
    }

    // temp MLP: j = tid>>5, c = tid&31
    {
        const int j = tid >> 5, c = tid & 31;
        const int r = min(r0 + j, B - 1);
        tmp[j][c] = fmaxf(fmaf(t[r], tW1[c], tb1[c]), 0.f);
    }
    __syncthreads();
    {
        const int j = tid >> 5, c = tid & 31;
        float a2 = tb2[c];
        for (int kk = 0; kk < 32; kk++) a2 = fmaf(tmp[j][kk], tW2[kk * 32 + c], a2);
        cat[j][256 + c] = a2;
    }
    __syncthreads();

    // h1 = relu(LN(cat @ fW1 + fb1))
#pragma unroll
    for (int j = 0; j < 4; j++) acc[j] = fb1[tid];
    for (int k = 0; k < 288; k++) {
        const float wv = fW1[k * HID + tid];
#pragma unroll
        for (int j = 0; j < 4; j++) acc[j] = fmaf(cat[j][k], wv, acc[j]);
    }
#pragma unroll
    for (int j = 0; j < 4; j++) {
        float mu  = block_sum128(acc[j], red, tid) * (1.f / 128.f);
        float d   = acc[j] - mu;
        float var = block_sum128(d * d, red, tid) * (1.f / 128.f);
        buf[j][tid] = fmaxf(d * rsqrtf(var + 1e-5f) * l1g[tid] + l1b[tid], 0.f);
    }
    __syncthreads();

    // h2 = relu(LN(buf @ fW2 + fb2)) width 64, then out = h2 @ fW3 + fb3.
    // Two passes: row j = p*2 + (tid>>6); wave-local (64-lane) reductions.
    const int c = tid & 63;
#pragma unroll
    for (int p = 0; p < 2; p++) {
        const int j = p * 2 + (tid >> 6);
        float a = fb2[c];
        for (int k = 0; k < 128; k++) a = fmaf(buf[j][k], fW2[k * 64 + c], a);
        float s = a;
#pragma unroll
        for (int o = 32; o > 0; o >>= 1) s += __shfl_down(s, o);
        const float mu = __shfl(s, 0) * (1.f / 64.f);
        const float d = a - mu;
        float s2 = d * d;
#pragma unroll
        for (int o = 32; o > 0; o >>= 1) s2 += __shfl_down(s2, o);
        const float var = __shfl(s2, 0) * (1.f / 64.f);
        const float h2 = fmaxf(d * rsqrtf(var + 1e-5f) * l2g[c] + l2b[c], 0.f);
        float cn = h2 * fW3[c];
#pragma unroll
        for (int o = 32; o > 0; o >>= 1) cn += __shfl_down(cn, o);
        if (c == 0) {
            const int r = r0 + j;
            if (r < B) out[r] = cn + fb3[0];
        }
    }
}

// ---------------------------------------------------------------------------
extern "C" void kernel_launch(void* const* d_in, const int* in_sizes, int n_in,
                              void* d_out, int out_size, void* d_ws, size_t ws_size,
                              hipStream_t stream) {
    const float* dx  = (const float*)d_in[0];
    const int*   de  = (const int*)d_in[1];
    const int*   db  = (const int*)d_in[2];
    const float* sx  = (const float*)d_in[3];
    const int*   se  = (const int*)d_in[4];
    const int*   sb  = (const int*)d_in[5];
    const float* t   = (const float*)d_in[6];
    const float* aW  = (const float*)d_in[7];
    const float* ab  = (const float*)d_in[8];
    const float* eps = (const float*)d_in[9];
    const float* W1  = (const float*)d_in[10];
    const float* b1  = (const float*)d_in[11];
    const float* g1  = (const float*)d_in[12];
    const float* be1 = (const float*)d_in[13];
    const float* m1  = (const float*)d_in[14];
    const float* v1  = (const float*)d_in[15];
    const float* W2  = (const float*)d_in[16];
    const float* b2  = (const float*)d_in[17];
    const float* g2  = (const float*)d_in[18];
    const float* be2 = (const float*)d_in[19];
    const float* m2  = (const float*)d_in[20];
    const float* v2  = (const float*)d_in[21];
    const float* tW1 = (const float*)d_in[22];
    const float* tb1 = (const float*)d_in[23];
    const float* tW2 = (const float*)d_in[24];
    const float* tb2 = (const float*)d_in[25];
    const float* iW  = (const float*)d_in[26];
    const float* ib  = (const float*)d_in[27];
    const float* ilg = (const float*)d_in[28];
    const float* ilb = (const float*)d_in[29];
    const float* fW1 = (const float*)d_in[30];
    const float* fb1 = (const float*)d_in[31];
    const float* l1g = (const float*)d_in[32];
    const float* l1b = (const float*)d_in[33];
    const float* fW2 = (const float*)d_in[34];
    const float* fb2 = (const float*)d_in[35];
    const float* l2g = (const float*)d_in[36];
    const float* l2b = (const float*)d_in[37];
    const float* fW3 = (const float*)d_in[38];
    const float* fb3 = (const float*)d_in[39];
    float* out = (float*)d_out;

    const int N  = in_sizes[0] / 9;
    const int Ed = in_sizes[1] / 2;
    const int Es = in_sizes[4] / 2;
    const int B  = in_sizes[6];
    const int nb = (N + 255) / 256;
    const int Emax = (Ed > Es) ? Ed : Es;

    // ---- workspace layout (ints first, then bf16/f32 buffers) ----
    char* w8 = (char*)d_ws;
    int* rpd   = (int*)w8;                   // N+1
    int* rps   = rpd + (N + 1);              // N+1
    int* cntd  = rps + (N + 1);              // N   -- cntd..cnt2s zeroed together (4N)
    int* cnts  = cntd + N;                   // N
    int* cnt2d = cnts + N;                   // N
    int* cnt2s = cnt2d + N;                  // N
    int* sid   = cnt2s + N;                  // Ed
    int* sis   = sid + Ed;                   // Es
    int* bsumd = sis + Es;                   // nb
    int* bsums = bsumd + nb;                 // nb
    uintptr_t foff = (((uintptr_t)(bsums + nb)) + 255) & ~(uintptr_t)255;

    const int WT = 3 * NLAYER * 128 * 256;
    u16* W1t = (u16*)foff;
    u16* W2t = W1t + WT;
    const size_t hS = (size_t)N * HID;
    u16* hbuf = W2t + WT;
    float* emb = (float*)(((uintptr_t)(hbuf + 3 * hS) + 255) & ~(uintptr_t)255);

    // ---- weight prep + CSR build ----
    prep_weights<<<(2 * WT + 255) / 256, 256, 0, stream>>>(W1, W2, W1t, W2t);
    (void)hipMemsetAsync(cntd, 0, (size_t)4 * N * sizeof(int), stream);
    {
        dim3 gh((Emax + 255) / 256, 2);
        hist2<<<gh, 256, 0, stream>>>(de, se, cntd, cnts, Ed, Es);
        dim3 gs1(nb, 2);
        scan1v<<<gs1, 256, 0, stream>>>(cntd, cnts, bsumd, bsums, N);
        scan2v<<<2, 256, 0, stream>>>(bsumd, bsums, nb);
        scan3v<<<gs1, 256, 0, stream>>>(cntd, cnts, bsumd, bsums, rpd, rps, N, Ed, Es);
        fill2<<<gh, 256, 0, stream>>>(de, se, rpd, rps, cnt2d, cnt2s, sid, sis, Ed, Es);
    }

    // ---- encoders (3 slots batched via grid.z) ----
    {
        dim3 ga((N * HID + 255) / 256, 1, 3);
        atom_kernel<<<ga, 256, 0, stream>>>(dx, sx, aW, ab, hbuf, N);
        for (int l = 0; l < NLAYER; l++) {
            dim3 gf((N + 127) / 128, 1, 3);
            fused_layer<<<gf, 256, 0, stream>>>(rpd, sid, rps, sis, hbuf, W1t, W2t,
                                                b1, g1, be1, m1, v1,
                                                b2, g2, be2, m2, v2,
                                                eps, hbuf, N, l);
        }
        dim3 gp(B, 1, 3);
        pool_kernel<<<gp, 128, 0, stream>>>(db, sb, hbuf, emb, N, B);
    }
    fusion_kernel<<<(B + 3) / 4, 128, 0, stream>>>(emb, t, tW1, tb1, tW2, tb2,
                                                   iW, ib, ilg, ilb, fW1, fb1, l1g, l1b,
                                                   fW2, fb2, l2g, l2b, fW3, fb3, out, B);
}

// Round 8
// 948.489 us; speedup vs baseline: 1.3926x; 1.0241x over previous
//
#include <hip/hip_runtime.h>

#define HID 128
#define NLAYER 4

typedef unsigned short u16;
typedef __attribute__((ext_vector_type(8))) unsigned short u16x8;
typedef __attribute__((ext_vector_type(8))) short short8;
typedef __attribute__((ext_vector_type(4))) float floatx4;

__device__ __forceinline__ float bf2f(u16 u) {
    union { unsigned int i; float f; } v; v.i = ((unsigned int)u) << 16; return v.f;
}
__device__ __forceinline__ u16 f2bf(float f) {
    union { float f; unsigned int i; } v; v.f = f;
    unsigned int r = v.i + 0x7FFFu + ((v.i >> 16) & 1u);
    return (u16)(r >> 16);
}

// ---------------------------------------------------------------------------
__device__ __forceinline__ int lowbound(const int* __restrict__ a, int n, int v) {
    int lo = 0, hi = n;
    while (lo < hi) {
        int mid = (lo + hi) >> 1;
        if (a[mid] < v) lo = mid + 1; else hi = mid;
    }
    return lo;
}

// ---------------------------------------------------------------------------
// Weight prep: fp32 -> bf16, transposed to [enc][l][n][k].
// ---------------------------------------------------------------------------
__global__ void prep_weights(const float* __restrict__ W1, const float* __restrict__ W2,
                             u16* __restrict__ W1t, u16* __restrict__ W2t) {
    const int T = 3 * NLAYER * 128 * 256;  // 393216
    int o = blockIdx.x * blockDim.x + threadIdx.x;
    if (o < T) {
        int k = o & 127, n = (o >> 7) & 255, el = o >> 15;
        W1t[o] = f2bf(W1[((size_t)el * 128 + k) * 256 + n]);
    } else if (o < 2 * T) {
        int o2 = o - T;
        int k = o2 & 255, n = (o2 >> 8) & 127, el = o2 >> 15;
        W2t[o2] = f2bf(W2[((size_t)el * 256 + k) * 128 + n]);
    }
}

// ---------------------------------------------------------------------------
// CSR build (R3 chain; per-node atomics have low contention at ~12 ops/node)
// ---------------------------------------------------------------------------
__global__ void hist2(const int* __restrict__ de, const int* __restrict__ se,
                      int* __restrict__ cntd, int* __restrict__ cnts, int Ed, int Es) {
    const int g = blockIdx.y;
    const int* ei = g ? se : de;
    int* cnt = g ? cnts : cntd;
    const int E = g ? Es : Ed;
    int e = blockIdx.x * 256 + threadIdx.x;
    if (e < E) atomicAdd(&cnt[ei[E + e]], 1);
}

__global__ __launch_bounds__(256) void scan1v(const int* __restrict__ cntd,
                                              const int* __restrict__ cnts,
                                              int* __restrict__ bsumd,
                                              int* __restrict__ bsums, int N) {
    const int g = blockIdx.y;
    const int* cnt = g ? cnts : cntd;
    int* bsum = g ? bsums : bsumd;
    __shared__ int s[256];
    int i = blockIdx.x * 256 + threadIdx.x;
    s[threadIdx.x] = (i < N) ? cnt[i] : 0;
    __syncthreads();
    for (int o = 128; o > 0; o >>= 1) {
        if (threadIdx.x < o) s[threadIdx.x] += s[threadIdx.x + o];
        __syncthreads();
    }
    if (threadIdx.x == 0) bsum[blockIdx.x] = s[0];
}

__global__ __launch_bounds__(256) void scan2v(int* __restrict__ bsumd,
                                              int* __restrict__ bsums, int nb) {
    int* bsum = blockIdx.x ? bsums : bsumd;
    __shared__ int s[256];
    __shared__ int carry;
    if (threadIdx.x == 0) carry = 0;
    __syncthreads();
    for (int base = 0; base < nb; base += 256) {
        int i = base + threadIdx.x;
        int v = (i < nb) ? bsum[i] : 0;
        s[threadIdx.x] = v;
        __syncthreads();
        for (int o = 1; o < 256; o <<= 1) {
            int tv = (threadIdx.x >= o) ? s[threadIdx.x - o] : 0;
            __syncthreads();
            s[threadIdx.x] += tv;
            __syncthreads();
        }
        int excl = carry + s[threadIdx.x] - v;
        if (i < nb) bsum[i] = excl;
        __syncthreads();
        if (threadIdx.x == 0) carry += s[255];
        __syncthreads();
    }
}

__global__ __launch_bounds__(256) void scan3v(const int* __restrict__ cntd,
                                              const int* __restrict__ cnts,
                                              const int* __restrict__ bsumd,
                                              const int* __restrict__ bsums,
                                              int* __restrict__ rpd, int* __restrict__ rps,
                                              int N, int Ed, int Es) {
    const int g = blockIdx.y;
    const int* cnt = g ? cnts : cntd;
    const int* bsum = g ? bsums : bsumd;
    int* rowptr = g ? rps : rpd;
    const int E = g ? Es : Ed;
    __shared__ int s[256];
    int i = blockIdx.x * 256 + threadIdx.x;
    int v = (i < N) ? cnt[i] : 0;
    s[threadIdx.x] = v;
    __syncthreads();
    for (int o = 1; o < 256; o <<= 1) {
        int tv = (threadIdx.x >= o) ? s[threadIdx.x - o] : 0;
        __syncthreads();
        s[threadIdx.x] += tv;
        __syncthreads();
    }
    if (i < N) rowptr[i] = bsum[blockIdx.x] + s[threadIdx.x] - v;
    if (i == 0 && blockIdx.x == 0) rowptr[N] = E;
}

__global__ void fill2(const int* __restrict__ de, const int* __restrict__ se,
                      const int* __restrict__ rpd, const int* __restrict__ rps,
                      int* __restrict__ cnt2d, int* __restrict__ cnt2s,
                      int* __restrict__ sid, int* __restrict__ sis, int Ed, int Es) {
    const int g = blockIdx.y;
    const int* ei = g ? se : de;
    const int* rowptr = g ? rps : rpd;
    int* cnt2 = g ? cnt2s : cnt2d;
    int* srcidx = g ? sis : sid;
    const int E = g ? Es : Ed;
    int e = blockIdx.x * 256 + threadIdx.x;
    if (e < E) {
        const int dst = ei[E + e];
        const int pos = rowptr[dst] + atomicAdd(&cnt2[dst], 1);
        srcidx[pos] = ei[e];
    }
}

// ---------------------------------------------------------------------------
// Atom encoder: h = x @ aW + ab  (fp32 compute, bf16 store). grid.z = slot.
// ---------------------------------------------------------------------------
__global__ void atom_kernel(const float* __restrict__ dx, const float* __restrict__ sx,
                            const float* __restrict__ aW, const float* __restrict__ ab,
                            u16* __restrict__ h, int N) {
    const int slot = blockIdx.z;
    long idx = (long)blockIdx.x * blockDim.x + threadIdx.x;
    if (idx >= (long)N * HID) return;
    const int n = (int)(idx >> 7), c = (int)(idx & 127);
    const float* x = (slot < 2) ? dx : sx;
    const float* W = aW + (size_t)slot * 9 * HID;
    float acc = ab[slot * HID + c];
#pragma unroll
    for (int k = 0; k < 9; k++) acc = fmaf(x[n * 9 + k], W[k * HID + c], acc);
    h[(size_t)slot * N * HID + idx] = f2bf(acc);
}

// ---------------------------------------------------------------------------
// Fused GIN layer, 64-row tiles (R6 post-mortem: 128-row tile needed 128 acc
// VGPRs -> ~2 blocks/CU -> 17% occupancy -> gather latency exposed).
// 64-row: acc1=64 regs, 4 gather passes, ~4 blocks/CU.
//   gather z (LDS, stride 136) -> GEMM1 64x256 -> z2 in LDS (stride 264)
//   -> GEMM2 64x128 -> BN2+ReLU -> h.
// MFMA 16x16x32 bf16, C/D: col=lane&15, row=(lane>>4)*4+reg [m89-verified].
// ---------------------------------------------------------------------------
__global__ __launch_bounds__(256, 4) void fused_layer(
    const int* __restrict__ rpd, const int* __restrict__ sid,
    const int* __restrict__ rps, const int* __restrict__ sis,
    const u16* __restrict__ h,
    const u16* __restrict__ W1t, const u16* __restrict__ W2t,
    const float* __restrict__ b1, const float* __restrict__ g1, const float* __restrict__ be1,
    const float* __restrict__ m1, const float* __restrict__ v1,
    const float* __restrict__ b2, const float* __restrict__ g2, const float* __restrict__ be2,
    const float* __restrict__ m2, const float* __restrict__ v2,
    const float* __restrict__ eps,
    u16* __restrict__ out, int M, int l) {

    const int slot = blockIdx.z;
    const int m0 = blockIdx.x * 64;
    const int el = slot * NLAYER + l;
    const u16* Wp1 = W1t + (size_t)el * (256 * 128);
    const u16* Wp2 = W2t + (size_t)el * (128 * 256);
    const size_t poff1 = (size_t)el * 256;
    const size_t poff2 = (size_t)el * 128;
    const int* rowptr = (slot < 2) ? rpd : rps;
    const int* srcidx = (slot < 2) ? sid : sis;
    const u16* hp = h + (size_t)slot * M * 128;

    __shared__ u16 sm[64 * 264];  // 33 KB: z tile (stride 136) then z2 (stride 264)

    const int tid = threadIdx.x;
    const int lane = tid & 63;
    const int w = tid >> 6;
    const int sl = lane & 15;
    const int k8 = lane >> 4;
    const int subbase = lane & 48;

    // ---- gather z tile into LDS (4 passes x 16 nodes, 16 lanes/node) ----
    {
        const float scale = 1.f + eps[slot * NLAYER + l];
        const int coff = sl * 8;
#pragma unroll
        for (int pass = 0; pass < 4; pass++) {
            const int row = pass * 16 + (tid >> 4);
            int node = m0 + row; if (node >= M) node = M - 1;
            const int lo = rowptr[node], hi = rowptr[node + 1];
            u16x8 hv = *(const u16x8*)(hp + (size_t)node * 128 + coff);
            float s[8];
#pragma unroll
            for (int i = 0; i < 8; i++) s[i] = bf2f(hv[i]) * scale;
            for (int base = lo; base < hi; base += 16) {
                const int cnt = min(16, hi - base);
                int idx = (sl < cnt) ? srcidx[base + sl] : 0;
                int j = 0;
                for (; j + 4 <= cnt; j += 4) {
                    const int s0 = __shfl(idx, subbase + j);
                    const int s1 = __shfl(idx, subbase + j + 1);
                    const int s2 = __shfl(idx, subbase + j + 2);
                    const int s3 = __shfl(idx, subbase + j + 3);
                    u16x8 v0 = *(const u16x8*)(hp + (size_t)s0 * 128 + coff);
                    u16x8 v1 = *(const u16x8*)(hp + (size_t)s1 * 128 + coff);
                    u16x8 v2 = *(const u16x8*)(hp + (size_t)s2 * 128 + coff);
                    u16x8 v3 = *(const u16x8*)(hp + (size_t)s3 * 128 + coff);
#pragma unroll
                    for (int i = 0; i < 8; i++)
                        s[i] += (bf2f(v0[i]) + bf2f(v1[i])) + (bf2f(v2[i]) + bf2f(v3[i]));
                }
                for (; j < cnt; j++) {
                    const int sj = __shfl(idx, subbase + j);
                    u16x8 v = *(const u16x8*)(hp + (size_t)sj * 128 + coff);
#pragma unroll
                    for (int i = 0; i < 8; i++) s[i] += bf2f(v[i]);
                }
            }
            u16x8 o;
#pragma unroll
            for (int i = 0; i < 8; i++) o[i] = f2bf(s[i]);
            *(u16x8*)&sm[row * 136 + coff] = o;
        }
    }
    __syncthreads();

    // ---- GEMM1: 64 x 256, K=128. Wave w owns cols [w*64, w*64+64) ----
    floatx4 acc1[4][4];
#pragma unroll
    for (int mt = 0; mt < 4; mt++)
#pragma unroll
        for (int nt = 0; nt < 4; nt++) acc1[mt][nt] = (floatx4)0.f;

#pragma unroll
    for (int ks = 0; ks < 4; ks++) {
        short8 a[4], b[4];
#pragma unroll
        for (int mt = 0; mt < 4; mt++)
            a[mt] = *(const short8*)&sm[(mt * 16 + sl) * 136 + ks * 32 + k8 * 8];
#pragma unroll
        for (int nt = 0; nt < 4; nt++) {
            const int n = w * 64 + nt * 16 + sl;
            b[nt] = *(const short8*)(Wp1 + (size_t)n * 128 + ks * 32 + k8 * 8);
        }
#pragma unroll
        for (int mt = 0; mt < 4; mt++)
#pragma unroll
            for (int nt = 0; nt < 4; nt++)
                acc1[mt][nt] = __builtin_amdgcn_mfma_f32_16x16x32_bf16(a[mt], b[nt], acc1[mt][nt], 0, 0, 0);
    }
    __syncthreads();  // z tile fully consumed

    // ---- z2 = relu(BN1(acc1)) into LDS stride 264 ----
#pragma unroll
    for (int nt = 0; nt < 4; nt++) {
        const int gcol = w * 64 + nt * 16 + sl;
        const float sc = g1[poff1 + gcol] * rsqrtf(v1[poff1 + gcol] + 1e-5f);
        const float sh = (b1[poff1 + gcol] - m1[poff1 + gcol]) * sc + be1[poff1 + gcol];
#pragma unroll
        for (int mt = 0; mt < 4; mt++) {
#pragma unroll
            for (int r = 0; r < 4; r++) {
                const int row = mt * 16 + k8 * 4 + r;
                sm[row * 264 + gcol] = f2bf(fmaxf(fmaf(acc1[mt][nt][r], sc, sh), 0.f));
            }
        }
    }
    __syncthreads();

    // ---- GEMM2: 64 x 128, K=256. Wave: wr rows-half, wc cols-half ----
    const int wr = w & 1, wc = w >> 1;
    floatx4 acc2[2][4];
#pragma unroll
    for (int mt = 0; mt < 2; mt++)
#pragma unroll
        for (int nt = 0; nt < 4; nt++) acc2[mt][nt] = (floatx4)0.f;

#pragma unroll
    for (int ks = 0; ks < 8; ks++) {
        short8 a[2], b[4];
#pragma unroll
        for (int mt = 0; mt < 2; mt++)
            a[mt] = *(const short8*)&sm[(wr * 32 + mt * 16 + sl) * 264 + ks * 32 + k8 * 8];
#pragma unroll
        for (int nt = 0; nt < 4; nt++) {
            const int n = wc * 64 + nt * 16 + sl;
            b[nt] = *(const short8*)(Wp2 + (size_t)n * 256 + ks * 32 + k8 * 8);
        }
#pragma unroll
        for (int mt = 0; mt < 2; mt++)
#pragma unroll
            for (int nt = 0; nt < 4; nt++)
                acc2[mt][nt] = __builtin_amdgcn_mfma_f32_16x16x32_bf16(a[mt], b[nt], acc2[mt][nt], 0, 0, 0);
    }

    // ---- BN2 + ReLU epilogue ----
    u16* outp = out + (size_t)slot * M * 128;
#pragma unroll
    for (int nt = 0; nt < 4; nt++) {
        const int col = wc * 64 + nt * 16 + sl;
        const float sc = g2[poff2 + col] * rsqrtf(v2[poff2 + col] + 1e-5f);
        const float sh = (b2[poff2 + col] - m2[poff2 + col]) * sc + be2[poff2 + col];
#pragma unroll
        for (int mt = 0; mt < 2; mt++) {
#pragma unroll
            for (int r = 0; r < 4; r++) {
                const int gr = m0 + wr * 32 + mt * 16 + k8 * 4 + r;
                if (gr < M)
                    outp[(size_t)gr * 128 + col] = f2bf(fmaxf(fmaf(acc2[mt][nt][r], sc, sh), 0.f));
            }
        }
    }
}

// ---------------------------------------------------------------------------
// Segment-mean pool (bat sorted). bf16 in, fp32 out.
// ---------------------------------------------------------------------------
__global__ __launch_bounds__(128) void pool_kernel(const int* __restrict__ db,
                                                   const int* __restrict__ sb,
                                                   const u16* __restrict__ h,
                                                   float* __restrict__ emb,
                                                   int N, int B) {
    const int slot = blockIdx.z;
    const int* bat = (slot < 2) ? db : sb;
    const int g = blockIdx.x;
    const int lo = lowbound(bat, N, g);
    const int hi = lowbound(bat, N, g + 1);
    const int c = threadIdx.x;
    float s = 0.f;
    const u16* hp = h + (size_t)slot * N * HID;
    for (int n = lo; n < hi; n++) s += bf2f(hp[(size_t)n * HID + c]);
    const float cnt = (float)(hi - lo);
    emb[((size_t)slot * B + g) * HID + c] = s / fmaxf(cnt, 1.f);
}

// ---------------------------------------------------------------------------
__device__ __forceinline__ float block_sum128(float x, float* red, int tid) {
    red[tid] = x;
    __syncthreads();
    if (tid < 64) {
        float v = red[tid] + red[tid + 64];
#pragma unroll
        for (int o = 32; o > 0; o >>= 1) v += __shfl_down(v, o);
        if (tid == 0) red[0] = v;
    }
    __syncthreads();
    float r = red[0];
    __syncthreads();
    return r;
}

// ---------------------------------------------------------------------------
// Fusion head, 4 rows/block with register-level weight reuse.
// ---------------------------------------------------------------------------
__global__ __launch_bounds__(128) void fusion_kernel(
    const float* __restrict__ emb, const float* __restrict__ t,
    const float* __restrict__ tW1, const float* __restrict__ tb1,
    const float* __restrict__ tW2, const float* __restrict__ tb2,
    const float* __restrict__ iW, const float* __restrict__ ib,
    const float* __restrict__ ilg, const float* __restrict__ ilb,
    const float* __restrict__ fW1, const float* __restrict__ fb1,
    const float* __restrict__ l1g, const float* __restrict__ l1b,
    const float* __restrict__ fW2, const float* __restrict__ fb2,
    const float* __restrict__ l2g, const float* __restrict__ l2b,
    const float* __restrict__ fW3, const float* __restrict__ fb3,
    float* __restrict__ out, int B) {
    const int r0 = blockIdx.x * 4;
    const int tid = threadIdx.x;
    __shared__ float cs[4][256];
    __shared__ float cat[4][288];
    __shared__ float buf[4][128];
    __shared__ float red[128];
    __shared__ float tmp[4][32];

#pragma unroll
    for (int j = 0; j < 4; j++) {
        const int r = min(r0 + j, B - 1);
        cs[j][tid]       = emb[((size_t)1 * B + r) * HID + tid];
        cs[j][128 + tid] = emb[((size_t)2 * B + r) * HID + tid];
        cat[j][tid]      = emb[((size_t)0 * B + r) * HID + tid];
    }
    __syncthreads();

    float acc[4];
#pragma unroll
    for (int j = 0; j < 4; j++) acc[j] = ib[tid];
    for (int k = 0; k < 256; k++) {
        const float wv = iW[k * HID + tid];
#pragma unroll
        for (int j = 0; j < 4; j++) acc[j] = fmaf(cs[j][k], wv, acc[j]);
    }
#pragma unroll
    for (int j = 0; j < 4; j++) {
        float mu  = block_sum128(acc[j], red, tid) * (1.f / 128.f);
        float d   = acc[j] - mu;
        float var = block_sum128(d * d, red, tid) * (1.f / 128.f);
        cat[j][128 + tid] = fmaxf(d * rsqrtf(var + 1e-5f) * ilg[tid] + ilb[tid], 0.f);
    }

    {
        const int j = tid >> 5, c = tid & 31;
        const int r = min(r0 + j, B - 1);
        tmp[j][c] = fmaxf(fmaf(t[r], tW1[c], tb1[c]), 0.f);
    }
    __syncthreads();
    {
        const int j = tid >> 5, c = tid & 31;
        float a2 = tb2[c];
        for (int kk = 0; kk < 32; kk++) a2 = fmaf(tmp[j][kk], tW2[kk * 32 + c], a2);
        cat[j][256 + c] = a2;
    }
    __syncthreads();

#pragma unroll
    for (int j = 0; j < 4; j++) acc[j] = fb1[tid];
    for (int k = 0; k < 288; k++) {
        const float wv = fW1[k * HID + tid];
#pragma unroll
        for (int j = 0; j < 4; j++) acc[j] = fmaf(cat[j][k], wv, acc[j]);
    }
#pragma unroll
    for (int j = 0; j < 4; j++) {
        float mu  = block_sum128(acc[j], red, tid) * (1.f / 128.f);
        float d   = acc[j] - mu;
        float var = block_sum128(d * d, red, tid) * (1.f / 128.f);
        buf[j][tid] = fmaxf(d * rsqrtf(var + 1e-5f) * l1g[tid] + l1b[tid], 0.f);
    }
    __syncthreads();

    const int c = tid & 63;
#pragma unroll
    for (int p = 0; p < 2; p++) {
        const int j = p * 2 + (tid >> 6);
        float a = fb2[c];
        for (int k = 0; k < 128; k++) a = fmaf(buf[j][k], fW2[k * 64 + c], a);
        float s = a;
#pragma unroll
        for (int o = 32; o > 0; o >>= 1) s += __shfl_down(s, o);
        const float mu = __shfl(s, 0) * (1.f / 64.f);
        const float d = a - mu;
        float s2 = d * d;
#pragma unroll
        for (int o = 32; o > 0; o >>= 1) s2 += __shfl_down(s2, o);
        const float var = __shfl(s2, 0) * (1.f / 64.f);
        const float h2 = fmaxf(d * rsqrtf(var + 1e-5f) * l2g[c] + l2b[c], 0.f);
        float cn = h2 * fW3[c];
#pragma unroll
        for (int o = 32; o > 0; o >>= 1) cn += __shfl_down(cn, o);
        if (c == 0) {
            const int r = r0 + j;
            if (r < B) out[r] = cn + fb3[0];
        }
    }
}

// ---------------------------------------------------------------------------
extern "C" void kernel_launch(void* const* d_in, const int* in_sizes, int n_in,
                              void* d_out, int out_size, void* d_ws, size_t ws_size,
                              hipStream_t stream) {
    const float* dx  = (const float*)d_in[0];
    const int*   de  = (const int*)d_in[1];
    const int*   db  = (const int*)d_in[2];
    const float* sx  = (const float*)d_in[3];
    const int*   se  = (const int*)d_in[4];
    const int*   sb  = (const int*)d_in[5];
    const float* t   = (const float*)d_in[6];
    const float* aW  = (const float*)d_in[7];
    const float* ab  = (const float*)d_in[8];
    const float* eps = (const float*)d_in[9];
    const float* W1  = (const float*)d_in[10];
    const float* b1  = (const float*)d_in[11];
    const float* g1  = (const float*)d_in[12];
    const float* be1 = (const float*)d_in[13];
    const float* m1  = (const float*)d_in[14];
    const float* v1  = (const float*)d_in[15];
    const float* W2  = (const float*)d_in[16];
    const float* b2  = (const float*)d_in[17];
    const float* g2  = (const float*)d_in[18];
    const float* be2 = (const float*)d_in[19];
    const float* m2  = (const float*)d_in[20];
    const float* v2  = (const float*)d_in[21];
    const float* tW1 = (const float*)d_in[22];
    const float* tb1 = (const float*)d_in[23];
    const float* tW2 = (const float*)d_in[24];
    const float* tb2 = (const float*)d_in[25];
    const float* iW  = (const float*)d_in[26];
    const float* ib  = (const float*)d_in[27];
    const float* ilg = (const float*)d_in[28];
    const float* ilb = (const float*)d_in[29];
    const float* fW1 = (const float*)d_in[30];
    const float* fb1 = (const float*)d_in[31];
    const float* l1g = (const float*)d_in[32];
    const float* l1b = (const float*)d_in[33];
    const float* fW2 = (const float*)d_in[34];
    const float* fb2 = (const float*)d_in[35];
    const float* l2g = (const float*)d_in[36];
    const float* l2b = (const float*)d_in[37];
    const float* fW3 = (const float*)d_in[38];
    const float* fb3 = (const float*)d_in[39];
    float* out = (float*)d_out;

    const int N  = in_sizes[0] / 9;
    const int Ed = in_sizes[1] / 2;
    const int Es = in_sizes[4] / 2;
    const int B  = in_sizes[6];
    const int nb = (N + 255) / 256;
    const int Emax = (Ed > Es) ? Ed : Es;

    // ---- workspace layout (ints first, then bf16/f32 buffers) ----
    char* w8 = (char*)d_ws;
    int* rpd   = (int*)w8;
    int* rps   = rpd + (N + 1);
    int* cntd  = rps + (N + 1);
    int* cnts  = cntd + N;
    int* cnt2d = cnts + N;
    int* cnt2s = cnt2d + N;
    int* sid   = cnt2s + N;
    int* sis   = sid + Ed;
    int* bsumd = sis + Es;
    int* bsums = bsumd + nb;
    uintptr_t foff = (((uintptr_t)(bsums + nb)) + 255) & ~(uintptr_t)255;

    const int WT = 3 * NLAYER * 128 * 256;
    u16* W1t = (u16*)foff;
    u16* W2t = W1t + WT;
    const size_t hS = (size_t)N * HID;
    u16* hbuf = W2t + WT;
    float* emb = (float*)(((uintptr_t)(hbuf + 3 * hS) + 255) & ~(uintptr_t)255);

    // ---- weight prep + CSR build ----
    prep_weights<<<(2 * WT + 255) / 256, 256, 0, stream>>>(W1, W2, W1t, W2t);
    (void)hipMemsetAsync(cntd, 0, (size_t)4 * N * sizeof(int), stream);
    {
        dim3 gh((Emax + 255) / 256, 2);
        hist2<<<gh, 256, 0, stream>>>(de, se, cntd, cnts, Ed, Es);
        dim3 gs1(nb, 2);
        scan1v<<<gs1, 256, 0, stream>>>(cntd, cnts, bsumd, bsums, N);
        scan2v<<<2, 256, 0, stream>>>(bsumd, bsums, nb);
        scan3v<<<gs1, 256, 0, stream>>>(cntd, cnts, bsumd, bsums, rpd, rps, N, Ed, Es);
        fill2<<<gh, 256, 0, stream>>>(de, se, rpd, rps, cnt2d, cnt2s, sid, sis, Ed, Es);
    }

    // ---- encoders (3 slots batched via grid.z) ----
    {
        dim3 ga((N * HID + 255) / 256, 1, 3);
        atom_kernel<<<ga, 256, 0, stream>>>(dx, sx, aW, ab, hbuf, N);
        for (int l = 0; l < NLAYER; l++) {
            dim3 gf((N + 63) / 64, 1, 3);
            fused_layer<<<gf, 256, 0, stream>>>(rpd, sid, rps, sis, hbuf, W1t, W2t,
                                                b1, g1, be1, m1, v1,
                                                b2, g2, be2, m2, v2,
                                                eps, hbuf, N, l);
        }
        dim3 gp(B, 1, 3);
        pool_kernel<<<gp, 128, 0, stream>>>(db, sb, hbuf, emb, N, B);
    }
    fusion_kernel<<<(B + 3) / 4, 128, 0, stream>>>(emb, t, tW1, tb1, tW2, tb2,
                                                   iW, ib, ilg, ilb, fW1, fb1, l1g, l1b,
                                                   fW2, fb2, l2g, l2b, fW3, fb3, out, B);
}

// Round 9
// 826.623 us; speedup vs baseline: 1.5979x; 1.1474x over previous
//
#include <hip/hip_runtime.h>

#define HID 128
#define NLAYER 4

typedef unsigned short u16;
typedef __attribute__((ext_vector_type(8))) unsigned short u16x8;
typedef __attribute__((ext_vector_type(8))) short short8;
typedef __attribute__((ext_vector_type(4))) float floatx4;

__device__ __forceinline__ float bf2f(u16 u) {
    union { unsigned int i; float f; } v; v.i = ((unsigned int)u) << 16; return v.f;
}
__device__ __forceinline__ u16 f2bf(float f) {
    union { float f; unsigned int i; } v; v.f = f;
    unsigned int r = v.i + 0x7FFFu + ((v.i >> 16) & 1u);
    return (u16)(r >> 16);
}

// ---------------------------------------------------------------------------
__device__ __forceinline__ int lowbound(const int* __restrict__ a, int n, int v) {
    int lo = 0, hi = n;
    while (lo < hi) {
        int mid = (lo + hi) >> 1;
        if (a[mid] < v) lo = mid + 1; else hi = mid;
    }
    return lo;
}

// ---------------------------------------------------------------------------
// Weight prep: fp32 -> bf16, transposed to [enc][l][n][k].
// ---------------------------------------------------------------------------
__global__ void prep_weights(const float* __restrict__ W1, const float* __restrict__ W2,
                             u16* __restrict__ W1t, u16* __restrict__ W2t) {
    const int T = 3 * NLAYER * 128 * 256;  // 393216
    int o = blockIdx.x * blockDim.x + threadIdx.x;
    if (o < T) {
        int k = o & 127, n = (o >> 7) & 255, el = o >> 15;
        W1t[o] = f2bf(W1[((size_t)el * 128 + k) * 256 + n]);
    } else if (o < 2 * T) {
        int o2 = o - T;
        int k = o2 & 255, n = (o2 >> 8) & 127, el = o2 >> 15;
        W2t[o2] = f2bf(W2[((size_t)el * 256 + k) * 128 + n]);
    }
}

// ---------------------------------------------------------------------------
// CSR build. Per-node atomics (~12 ops/node, low contention — R4's bucketed
// variant serialized at ~767 ops/bucket and regressed 2x; keep per-node).
// srcidx stored as u16 (N < 65536): halves fill write-amp + gather idx bytes.
// ---------------------------------------------------------------------------
__global__ void hist2(const int* __restrict__ de, const int* __restrict__ se,
                      int* __restrict__ cntd, int* __restrict__ cnts, int Ed, int Es) {
    const int g = blockIdx.y;
    const int* ei = g ? se : de;
    int* cnt = g ? cnts : cntd;
    const int E = g ? Es : Ed;
    int e = blockIdx.x * 256 + threadIdx.x;
    if (e < E) atomicAdd(&cnt[ei[E + e]], 1);
}

__global__ __launch_bounds__(256) void scan1v(const int* __restrict__ cntd,
                                              const int* __restrict__ cnts,
                                              int* __restrict__ bsumd,
                                              int* __restrict__ bsums, int N) {
    const int g = blockIdx.y;
    const int* cnt = g ? cnts : cntd;
    int* bsum = g ? bsums : bsumd;
    __shared__ int s[256];
    int i = blockIdx.x * 256 + threadIdx.x;
    s[threadIdx.x] = (i < N) ? cnt[i] : 0;
    __syncthreads();
    for (int o = 128; o > 0; o >>= 1) {
        if (threadIdx.x < o) s[threadIdx.x] += s[threadIdx.x + o];
        __syncthreads();
    }
    if (threadIdx.x == 0) bsum[blockIdx.x] = s[0];
}

__global__ __launch_bounds__(256) void scan2v(int* __restrict__ bsumd,
                                              int* __restrict__ bsums, int nb) {
    int* bsum = blockIdx.x ? bsums : bsumd;
    __shared__ int s[256];
    __shared__ int carry;
    if (threadIdx.x == 0) carry = 0;
    __syncthreads();
    for (int base = 0; base < nb; base += 256) {
        int i = base + threadIdx.x;
        int v = (i < nb) ? bsum[i] : 0;
        s[threadIdx.x] = v;
        __syncthreads();
        for (int o = 1; o < 256; o <<= 1) {
            int tv = (threadIdx.x >= o) ? s[threadIdx.x - o] : 0;
            __syncthreads();
            s[threadIdx.x] += tv;
            __syncthreads();
        }
        int excl = carry + s[threadIdx.x] - v;
        if (i < nb) bsum[i] = excl;
        __syncthreads();
        if (threadIdx.x == 0) carry += s[255];
        __syncthreads();
    }
}

__global__ __launch_bounds__(256) void scan3v(const int* __restrict__ cntd,
                                              const int* __restrict__ cnts,
                                              const int* __restrict__ bsumd,
                                              const int* __restrict__ bsums,
                                              int* __restrict__ rpd, int* __restrict__ rps,
                                              int N, int Ed, int Es) {
    const int g = blockIdx.y;
    const int* cnt = g ? cnts : cntd;
    const int* bsum = g ? bsums : bsumd;
    int* rowptr = g ? rps : rpd;
    const int E = g ? Es : Ed;
    __shared__ int s[256];
    int i = blockIdx.x * 256 + threadIdx.x;
    int v = (i < N) ? cnt[i] : 0;
    s[threadIdx.x] = v;
    __syncthreads();
    for (int o = 1; o < 256; o <<= 1) {
        int tv = (threadIdx.x >= o) ? s[threadIdx.x - o] : 0;
        __syncthreads();
        s[threadIdx.x] += tv;
        __syncthreads();
    }
    if (i < N) rowptr[i] = bsum[blockIdx.x] + s[threadIdx.x] - v;
    if (i == 0 && blockIdx.x == 0) rowptr[N] = E;
}

// fill via atomicSub on the histogram counts (cnt is dead after scan3v) —
// no cnt2 arrays, half the memset. Positions filled in reverse: harmless.
__global__ void fill2(const int* __restrict__ de, const int* __restrict__ se,
                      const int* __restrict__ rpd, const int* __restrict__ rps,
                      int* __restrict__ cntd, int* __restrict__ cnts,
                      u16* __restrict__ sid, u16* __restrict__ sis, int Ed, int Es) {
    const int g = blockIdx.y;
    const int* ei = g ? se : de;
    const int* rowptr = g ? rps : rpd;
    int* cnt = g ? cnts : cntd;
    u16* srcidx = g ? sis : sid;
    const int E = g ? Es : Ed;
    int e = blockIdx.x * 256 + threadIdx.x;
    if (e < E) {
        const int dst = ei[E + e];
        const int pos = rowptr[dst] + atomicSub(&cnt[dst], 1) - 1;
        srcidx[pos] = (u16)ei[e];
    }
}

// ---------------------------------------------------------------------------
// Atom encoder: h = x @ aW + ab  (fp32 compute, bf16 store). grid.z = slot.
// ---------------------------------------------------------------------------
__global__ void atom_kernel(const float* __restrict__ dx, const float* __restrict__ sx,
                            const float* __restrict__ aW, const float* __restrict__ ab,
                            u16* __restrict__ h, int N) {
    const int slot = blockIdx.z;
    long idx = (long)blockIdx.x * blockDim.x + threadIdx.x;
    if (idx >= (long)N * HID) return;
    const int n = (int)(idx >> 7), c = (int)(idx & 127);
    const float* x = (slot < 2) ? dx : sx;
    const float* W = aW + (size_t)slot * 9 * HID;
    float acc = ab[slot * HID + c];
#pragma unroll
    for (int k = 0; k < 9; k++) acc = fmaf(x[n * 9 + k], W[k * HID + c], acc);
    h[(size_t)slot * N * HID + idx] = f2bf(acc);
}

// ---------------------------------------------------------------------------
// Gather-aggregate (separate kernel: VGPR=12 -> 32 waves/CU, max latency
// hiding — merging into the GEMM kernel capped waves at ~12 and regressed).
// z[n] = (1+eps)*h[n] + sum h[src]. 16 lanes/node, u16x8 loads, shfl idx bcast.
// ---------------------------------------------------------------------------
__global__ __launch_bounds__(256) void gather_agg(
    const int* __restrict__ rpd, const u16* __restrict__ sid,
    const int* __restrict__ rps, const u16* __restrict__ sis,
    const u16* __restrict__ h, u16* __restrict__ z,
    const float* __restrict__ eps, int N, int l) {
    const int slot = blockIdx.z;
    const int node = blockIdx.x * 16 + (threadIdx.x >> 4);
    if (node >= N) return;
    const int lane = threadIdx.x & 63;
    const int sl = lane & 15;
    const int subbase = lane & 48;
    const int* rowptr = (slot < 2) ? rpd : rps;
    const u16* srcidx = (slot < 2) ? sid : sis;
    const int lo = rowptr[node], hi = rowptr[node + 1];
    const u16* hp = h + (size_t)slot * N * HID;
    const int coff = sl * 8;

    u16x8 hv = *(const u16x8*)(hp + (size_t)node * HID + coff);
    const float scale = 1.f + eps[slot * NLAYER + l];
    float s[8];
#pragma unroll
    for (int i = 0; i < 8; i++) s[i] = bf2f(hv[i]) * scale;

    for (int base = lo; base < hi; base += 16) {
        const int c16 = min(16, hi - base);
        int idx = (sl < c16) ? (int)srcidx[base + sl] : 0;
        int j = 0;
        for (; j + 4 <= c16; j += 4) {
            const int s0 = __shfl(idx, subbase + j);
            const int s1 = __shfl(idx, subbase + j + 1);
            const int s2 = __shfl(idx, subbase + j + 2);
            const int s3 = __shfl(idx, subbase + j + 3);
            u16x8 v0 = *(const u16x8*)(hp + (size_t)s0 * HID + coff);
            u16x8 v1 = *(const u16x8*)(hp + (size_t)s1 * HID + coff);
            u16x8 v2 = *(const u16x8*)(hp + (size_t)s2 * HID + coff);
            u16x8 v3 = *(const u16x8*)(hp + (size_t)s3 * HID + coff);
#pragma unroll
            for (int i = 0; i < 8; i++)
                s[i] += (bf2f(v0[i]) + bf2f(v1[i])) + (bf2f(v2[i]) + bf2f(v3[i]));
        }
        for (; j < c16; j++) {
            const int sj = __shfl(idx, subbase + j);
            u16x8 v = *(const u16x8*)(hp + (size_t)sj * HID + coff);
#pragma unroll
            for (int i = 0; i < 8; i++) s[i] += bf2f(v[i]);
        }
    }
    u16x8 o;
#pragma unroll
    for (int i = 0; i < 8; i++) o[i] = f2bf(s[i]);
    *(u16x8*)(z + (size_t)slot * N * HID + (size_t)node * HID + coff) = o;
}

// ---------------------------------------------------------------------------
// Fused GEMM-only GIN layer (R4-proven, <72us/dispatch):
//   h_out = relu(BN2( relu(BN1(z@W1+b1)) @ W2 + b2 ))
// Block 256 thr = 4 waves; 128 rows/block. LDS 128x136 u16 reused z -> z2.
// MFMA 16x16x32 bf16, C/D: col=lane&15, row=(lane>>4)*4+reg [m89-verified].
// ---------------------------------------------------------------------------
__global__ __launch_bounds__(256, 2) void fused_layer(
    const u16* __restrict__ A, const u16* __restrict__ W1t, const u16* __restrict__ W2t,
    const float* __restrict__ b1, const float* __restrict__ g1, const float* __restrict__ be1,
    const float* __restrict__ m1, const float* __restrict__ v1,
    const float* __restrict__ b2, const float* __restrict__ g2, const float* __restrict__ be2,
    const float* __restrict__ m2, const float* __restrict__ v2,
    u16* __restrict__ out, int M, int l) {

    const int slot = blockIdx.z;
    const int m0 = blockIdx.x * 128;
    const u16* Ap  = A + (size_t)slot * M * 128;
    const int el = slot * NLAYER + l;
    const u16* Wp1 = W1t + (size_t)el * (256 * 128);
    const u16* Wp2 = W2t + (size_t)el * (128 * 256);
    const size_t poff1 = (size_t)el * 256;
    const size_t poff2 = (size_t)el * 128;

    __shared__ u16 sm[128 * 136];  // 34.8 KB, z tile then z2 halves

    const int tid = threadIdx.x;
    const int lane = tid & 63;
    const int w = tid >> 6;
    const int sl = lane & 15;
    const int k8 = lane >> 4;

    // ---- stage z tile from global ----
    {
        const int rp = tid >> 4;
        const int kc = (tid & 15) * 8;
#pragma unroll
        for (int p = 0; p < 8; p++) {
            const int row = p * 16 + rp;
            int gr = m0 + row; if (gr >= M) gr = M - 1;
            *(uint4*)&sm[row * 136 + kc] = *(const uint4*)(Ap + (size_t)gr * 128 + kc);
        }
    }
    __syncthreads();

    // ---- GEMM1: 128 x 256, K=128 ----
    floatx4 acc1[8][4];
#pragma unroll
    for (int mt = 0; mt < 8; mt++)
#pragma unroll
        for (int c = 0; c < 4; c++) acc1[mt][c] = (floatx4)0.f;

#pragma unroll
    for (int ks = 0; ks < 4; ks++) {
        short8 a[8], b[4];
#pragma unroll
        for (int mt = 0; mt < 8; mt++)
            a[mt] = *(const short8*)&sm[(mt * 16 + sl) * 136 + ks * 32 + k8 * 8];
#pragma unroll
        for (int c = 0; c < 4; c++) {
            const int n = (c * 4 + w) * 16 + sl;
            b[c] = *(const short8*)(Wp1 + (size_t)n * 128 + ks * 32 + k8 * 8);
        }
#pragma unroll
        for (int mt = 0; mt < 8; mt++)
#pragma unroll
            for (int c = 0; c < 4; c++)
                acc1[mt][c] = __builtin_amdgcn_mfma_f32_16x16x32_bf16(a[mt], b[c], acc1[mt][c], 0, 0, 0);
    }
    __syncthreads();  // z tile fully consumed

    // ---- z2 halves + GEMM2 ----
    const int wr = w & 1, wc = w >> 1;
    floatx4 acc2[4][4];
#pragma unroll
    for (int mt = 0; mt < 4; mt++)
#pragma unroll
        for (int nt = 0; nt < 4; nt++) acc2[mt][nt] = (floatx4)0.f;

#pragma unroll
    for (int part = 0; part < 2; part++) {
#pragma unroll
        for (int c = part * 2; c < part * 2 + 2; c++) {
            const int gcol = (c * 4 + w) * 16 + sl;
            const int lcol = gcol - part * 128;
            const float sc = g1[poff1 + gcol] * rsqrtf(v1[poff1 + gcol] + 1e-5f);
            const float sh = (b1[poff1 + gcol] - m1[poff1 + gcol]) * sc + be1[poff1 + gcol];
#pragma unroll
            for (int mt = 0; mt < 8; mt++) {
#pragma unroll
                for (int r = 0; r < 4; r++) {
                    const int m = mt * 16 + k8 * 4 + r;
                    sm[m * 136 + lcol] = f2bf(fmaxf(fmaf(acc1[mt][c][r], sc, sh), 0.f));
                }
            }
        }
        __syncthreads();
#pragma unroll
        for (int ks = 0; ks < 4; ks++) {
            short8 a[4], b[4];
#pragma unroll
            for (int mt = 0; mt < 4; mt++)
                a[mt] = *(const short8*)&sm[(wr * 64 + mt * 16 + sl) * 136 + ks * 32 + k8 * 8];
#pragma unroll
            for (int nt = 0; nt < 4; nt++) {
                const int n = wc * 64 + nt * 16 + sl;
                b[nt] = *(const short8*)(Wp2 + (size_t)n * 256 + part * 128 + ks * 32 + k8 * 8);
            }
#pragma unroll
            for (int mt = 0; mt < 4; mt++)
#pragma unroll
                for (int nt = 0; nt < 4; nt++)
                    acc2[mt][nt] = __builtin_amdgcn_mfma_f32_16x16x32_bf16(a[mt], b[nt], acc2[mt][nt], 0, 0, 0);
        }
        if (part == 0) __syncthreads();
    }

    // ---- BN2 + ReLU epilogue ----
    u16* outp = out + (size_t)slot * M * 128;
#pragma unroll
    for (int nt = 0; nt < 4; nt++) {
        const int col = wc * 64 + nt * 16 + sl;
        const float sc = g2[poff2 + col] * rsqrtf(v2[poff2 + col] + 1e-5f);
        const float sh = (b2[poff2 + col] - m2[poff2 + col]) * sc + be2[poff2 + col];
#pragma unroll
        for (int mt = 0; mt < 4; mt++) {
#pragma unroll
            for (int r = 0; r < 4; r++) {
                const int gr = m0 + wr * 64 + mt * 16 + k8 * 4 + r;
                if (gr < M)
                    outp[(size_t)gr * 128 + col] = f2bf(fmaxf(fmaf(acc2[mt][nt][r], sc, sh), 0.f));
            }
        }
    }
}

// ---------------------------------------------------------------------------
// Segment-mean pool (bat sorted). bf16 in, fp32 out.
// ---------------------------------------------------------------------------
__global__ __launch_bounds__(128) void pool_kernel(const int* __restrict__ db,
                                                   const int* __restrict__ sb,
                                                   const u16* __restrict__ h,
                                                   float* __restrict__ emb,
                                                   int N, int B) {
    const int slot = blockIdx.z;
    const int* bat = (slot < 2) ? db : sb;
    const int g = blockIdx.x;
    const int lo = lowbound(bat, N, g);
    const int hi = lowbound(bat, N, g + 1);
    const int c = threadIdx.x;
    float s = 0.f;
    const u16* hp = h + (size_t)slot * N * HID;
    for (int n = lo; n < hi; n++) s += bf2f(hp[(size_t)n * HID + c]);
    const float cnt = (float)(hi - lo);
    emb[((size_t)slot * B + g) * HID + c] = s / fmaxf(cnt, 1.f);
}

// ---------------------------------------------------------------------------
__device__ __forceinline__ float block_sum128(float x, float* red, int tid) {
    red[tid] = x;
    __syncthreads();
    if (tid < 64) {
        float v = red[tid] + red[tid + 64];
#pragma unroll
        for (int o = 32; o > 0; o >>= 1) v += __shfl_down(v, o);
        if (tid == 0) red[0] = v;
    }
    __syncthreads();
    float r = red[0];
    __syncthreads();
    return r;
}

// ---------------------------------------------------------------------------
// Fusion head, 4 rows/block with register-level weight reuse.
// ---------------------------------------------------------------------------
__global__ __launch_bounds__(128) void fusion_kernel(
    const float* __restrict__ emb, const float* __restrict__ t,
    const float* __restrict__ tW1, const float* __restrict__ tb1,
    const float* __restrict__ tW2, const float* __restrict__ tb2,
    const float* __restrict__ iW, const float* __restrict__ ib,
    const float* __restrict__ ilg, const float* __restrict__ ilb,
    const float* __restrict__ fW1, const float* __restrict__ fb1,
    const float* __restrict__ l1g, const float* __restrict__ l1b,
    const float* __restrict__ fW2, const float* __restrict__ fb2,
    const float* __restrict__ l2g, const float* __restrict__ l2b,
    const float* __restrict__ fW3, const float* __restrict__ fb3,
    float* __restrict__ out, int B) {
    const int r0 = blockIdx.x * 4;
    const int tid = threadIdx.x;
    __shared__ float cs[4][256];
    __shared__ float cat[4][288];
    __shared__ float buf[4][128];
    __shared__ float red[128];
    __shared__ float tmp[4][32];

#pragma unroll
    for (int j = 0; j < 4; j++) {
        const int r = min(r0 + j, B - 1);
        cs[j][tid]       = emb[((size_t)1 * B + r) * HID + tid];
        cs[j][128 + tid] = emb[((size_t)2 * B + r) * HID + tid];
        cat[j][tid]      = emb[((size_t)0 * B + r) * HID + tid];
    }
    __syncthreads();

    float acc[4];
#pragma unroll
    for (int j = 0; j < 4; j++) acc[j] = ib[tid];
    for (int k = 0; k < 256; k++) {
        const float wv = iW[k * HID + tid];
#pragma unroll
        for (int j = 0; j < 4; j++) acc[j] = fmaf(cs[j][k], wv, acc[j]);
    }
#pragma unroll
    for (int j = 0; j < 4; j++) {
        float mu  = block_sum128(acc[j], red, tid) * (1.f / 128.f);
        float d   = acc[j] - mu;
        float var = block_sum128(d * d, red, tid) * (1.f / 128.f);
        cat[j][128 + tid] = fmaxf(d * rsqrtf(var + 1e-5f) * ilg[tid] + ilb[tid], 0.f);
    }

    {
        const int j = tid >> 5, c = tid & 31;
        const int r = min(r0 + j, B - 1);
        tmp[j][c] = fmaxf(fmaf(t[r], tW1[c], tb1[c]), 0.f);
    }
    __syncthreads();
    {
        const int j = tid >> 5, c = tid & 31;
        float a2 = tb2[c];
        for (int kk = 0; kk < 32; kk++) a2 = fmaf(tmp[j][kk], tW2[kk * 32 + c], a2);
        cat[j][256 + c] = a2;
    }
    __syncthreads();

#pragma unroll
    for (int j = 0; j < 4; j++) acc[j] = fb1[tid];
    for (int k = 0; k < 288; k++) {
        const float wv = fW1[k * HID + tid];
#pragma unroll
        for (int j = 0; j < 4; j++) acc[j] = fmaf(cat[j][k], wv, acc[j]);
    }
#pragma unroll
    for (int j = 0; j < 4; j++) {
        float mu  = block_sum128(acc[j], red, tid) * (1.f / 128.f);
        float d   = acc[j] - mu;
        float var = block_sum128(d * d, red, tid) * (1.f / 128.f);
        buf[j][tid] = fmaxf(d * rsqrtf(var + 1e-5f) * l1g[tid] + l1b[tid], 0.f);
    }
    __syncthreads();

    const int c = tid & 63;
#pragma unroll
    for (int p = 0; p < 2; p++) {
        const int j = p * 2 + (tid >> 6);
        float a = fb2[c];
        for (int k = 0; k < 128; k++) a = fmaf(buf[j][k], fW2[k * 64 + c], a);
        float s = a;
#pragma unroll
        for (int o = 32; o > 0; o >>= 1) s += __shfl_down(s, o);
        const float mu = __shfl(s, 0) * (1.f / 64.f);
        const float d = a - mu;
        float s2 = d * d;
#pragma unroll
        for (int o = 32; o > 0; o >>= 1) s2 += __shfl_down(s2, o);
        const float var = __shfl(s2, 0) * (1.f / 64.f);
        const float h2 = fmaxf(d * rsqrtf(var + 1e-5f) * l2g[c] + l2b[c], 0.f);
        float cn = h2 * fW3[c];
#pragma unroll
        for (int o = 32; o > 0; o >>= 1) cn += __shfl_down(cn, o);
        if (c == 0) {
            const int r = r0 + j;
            if (r < B) out[r] = cn + fb3[0];
        }
    }
}

// ---------------------------------------------------------------------------
extern "C" void kernel_launch(void* const* d_in, const int* in_sizes, int n_in,
                              void* d_out, int out_size, void* d_ws, size_t ws_size,
                              hipStream_t stream) {
    const float* dx  = (const float*)d_in[0];
    const int*   de  = (const int*)d_in[1];
    const int*   db  = (const int*)d_in[2];
    const float* sx  = (const float*)d_in[3];
    const int*   se  = (const int*)d_in[4];
    const int*   sb  = (const int*)d_in[5];
    const float* t   = (const float*)d_in[6];
    const float* aW  = (const float*)d_in[7];
    const float* ab  = (const float*)d_in[8];
    const float* eps = (const float*)d_in[9];
    const float* W1  = (const float*)d_in[10];
    const float* b1  = (const float*)d_in[11];
    const float* g1  = (const float*)d_in[12];
    const float* be1 = (const float*)d_in[13];
    const float* m1  = (const float*)d_in[14];
    const float* v1  = (const float*)d_in[15];
    const float* W2  = (const float*)d_in[16];
    const float* b2  = (const float*)d_in[17];
    const float* g2  = (const float*)d_in[18];
    const float* be2 = (const float*)d_in[19];
    const float* m2  = (const float*)d_in[20];
    const float* v2  = (const float*)d_in[21];
    const float* tW1 = (const float*)d_in[22];
    const float* tb1 = (const float*)d_in[23];
    const float* tW2 = (const float*)d_in[24];
    const float* tb2 = (const float*)d_in[25];
    const float* iW  = (const float*)d_in[26];
    const float* ib  = (const float*)d_in[27];
    const float* ilg = (const float*)d_in[28];
    const float* ilb = (const float*)d_in[29];
    const float* fW1 = (const float*)d_in[30];
    const float* fb1 = (const float*)d_in[31];
    const float* l1g = (const float*)d_in[32];
    const float* l1b = (const float*)d_in[33];
    const float* fW2 = (const float*)d_in[34];
    const float* fb2 = (const float*)d_in[35];
    const float* l2g = (const float*)d_in[36];
    const float* l2b = (const float*)d_in[37];
    const float* fW3 = (const float*)d_in[38];
    const float* fb3 = (const float*)d_in[39];
    float* out = (float*)d_out;

    const int N  = in_sizes[0] / 9;
    const int Ed = in_sizes[1] / 2;
    const int Es = in_sizes[4] / 2;
    const int B  = in_sizes[6];
    const int nb = (N + 255) / 256;
    const int Emax = (Ed > Es) ? Ed : Es;

    // ---- workspace layout (ints, u16 idx, then bf16/f32 buffers) ----
    char* w8 = (char*)d_ws;
    int* rpd   = (int*)w8;
    int* rps   = rpd + (N + 1);
    int* cntd  = rps + (N + 1);
    int* cnts  = cntd + N;
    int* bsumd = cnts + N;
    int* bsums = bsumd + nb;
    u16* sid   = (u16*)(bsums + nb);
    u16* sis   = sid + Ed;
    uintptr_t foff = (((uintptr_t)(sis + Es)) + 255) & ~(uintptr_t)255;

    const int WT = 3 * NLAYER * 128 * 256;
    u16* W1t = (u16*)foff;
    u16* W2t = W1t + WT;
    const size_t hS = (size_t)N * HID;
    u16* hbuf = W2t + WT;
    u16* zbuf = hbuf + 3 * hS;
    float* emb = (float*)(((uintptr_t)(zbuf + 3 * hS) + 255) & ~(uintptr_t)255);

    // ---- weight prep + CSR build ----
    prep_weights<<<(2 * WT + 255) / 256, 256, 0, stream>>>(W1, W2, W1t, W2t);
    (void)hipMemsetAsync(cntd, 0, (size_t)2 * N * sizeof(int), stream);
    {
        dim3 gh((Emax + 255) / 256, 2);
        hist2<<<gh, 256, 0, stream>>>(de, se, cntd, cnts, Ed, Es);
        dim3 gs1(nb, 2);
        scan1v<<<gs1, 256, 0, stream>>>(cntd, cnts, bsumd, bsums, N);
        scan2v<<<2, 256, 0, stream>>>(bsumd, bsums, nb);
        scan3v<<<gs1, 256, 0, stream>>>(cntd, cnts, bsumd, bsums, rpd, rps, N, Ed, Es);
        fill2<<<gh, 256, 0, stream>>>(de, se, rpd, rps, cntd, cnts, sid, sis, Ed, Es);
    }

    // ---- encoders (3 slots batched via grid.z) ----
    {
        dim3 ga((N * HID + 255) / 256, 1, 3);
        atom_kernel<<<ga, 256, 0, stream>>>(dx, sx, aW, ab, hbuf, N);
        for (int l = 0; l < NLAYER; l++) {
            dim3 gg((N + 15) / 16, 1, 3);
            gather_agg<<<gg, 256, 0, stream>>>(rpd, sid, rps, sis, hbuf, zbuf, eps, N, l);
            dim3 gf((N + 127) / 128, 1, 3);
            fused_layer<<<gf, 256, 0, stream>>>(zbuf, W1t, W2t,
                                                b1, g1, be1, m1, v1,
                                                b2, g2, be2, m2, v2,
                                                hbuf, N, l);
        }
        dim3 gp(B, 1, 3);
        pool_kernel<<<gp, 128, 0, stream>>>(db, sb, hbuf, emb, N, B);
    }
    fusion_kernel<<<(B + 3) / 4, 128, 0, stream>>>(emb, t, tW1, tb1, tW2, tb2,
                                                   iW, ib, ilg, ilb, fW1, fb1, l1g, l1b,
                                                   fW2, fb2, l2g, l2b, fW3, fb3, out, B);
}